// Round 2
// 1726.134 us; speedup vs baseline: 1.2191x; 1.2191x over previous
//
#include <hip/hip_runtime.h>
#include <math.h>

typedef unsigned int u32;
typedef unsigned short u16;

#define N_NODES 100000
#define N_EDGES 1000000
#define NB      64
#define NODES_PER_G 1562   // N // B; graph 63 holds 1594
#define CH_PER_G 100       // ceil(1594/16)

typedef __attribute__((ext_vector_type(8))) short bf16x8;   // 8 bf16 = 4 VGPR
typedef __attribute__((ext_vector_type(4))) float f32x4;
#define MFMA16 __builtin_amdgcn_mfma_f32_16x16x32_bf16

__device__ __forceinline__ float sigmoidf_(float x){ return 1.f/(1.f+__expf(-x)); }
__device__ __forceinline__ float ftanh(float x){
  float e = __expf(-2.f*fabsf(x));
  float t = (1.f - e)/(1.f + e);
  return copysignf(t, x);
}

// streaming 128-dot: weights from global (L2-hot), x from LDS
__device__ __forceinline__ float dots(const float* w, const float* x){
  const float4* w4 = (const float4*)w;
  float a = 0.f;
#pragma unroll 8
  for(int i=0;i<32;i++){
    float4 t = w4[i];
    a = fmaf(t.x, x[4*i+0], a);
    a = fmaf(t.y, x[4*i+1], a);
    a = fmaf(t.z, x[4*i+2], a);
    a = fmaf(t.w, x[4*i+3], a);
  }
  return a;
}

// Dekker split: x = hi + lo, both bf16 (truncation); residual ~2^-16 relative
__device__ __forceinline__ void cvt2(float a, float b, u32 &hi, u32 &lo){
  u32 ab = __float_as_uint(a), bb = __float_as_uint(b);
  hi = (ab>>16) | (bb & 0xffff0000u);
  float ar = a - __uint_as_float(ab & 0xffff0000u);
  float br = b - __uint_as_float(bb & 0xffff0000u);
  lo = (__float_as_uint(ar)>>16) | (__float_as_uint(br) & 0xffff0000u);
}

// ------------- one-time weight split: fp32 -> bf16 hi/lo arrays in ws -------------
// layout (flat u16 index): [E_w 32768][gmA_w 16384][gm_wih 49152][gm_whh 49152]
__global__ __launch_bounds__(256) void k_prep(const float* __restrict__ ew,
                    const float* __restrict__ ga,
                    const float* __restrict__ wih,
                    const float* __restrict__ whh,
                    u16* __restrict__ hi, u16* __restrict__ lo){
  int i = blockIdx.x*256 + threadIdx.x;
  float x;
  if(i < 32768) x = ew[i];
  else if(i < 49152) x = ga[i-32768];
  else if(i < 98304) x = wih[i-49152];
  else if(i < 147456) x = whh[i-98304];
  else return;
  u32 b = __float_as_uint(x);
  u16 h = (u16)(b>>16);
  float hf = __uint_as_float((u32)h<<16);
  float l = x - hf;
  hi[i] = h;
  lo[i] = (u16)(__float_as_uint(l)>>16);
}

// ---------------- per-graph precompute: s2s, s2m, w2(=dsup*mC), gmB_lin ----------
__global__ __launch_bounds__(128,4) void k_sup(const float* __restrict__ s,
                      const float* A_w, const float* A_b,
                      const float* C_w, const float* C_b,
                      const float* mB_w, const float* mB_b, const float* mC_w,
                      const float* gmB_w, const float* gmB_b,
                      float* s2s, float* s2m_g, float* w2, float* gmB_lin){
  int b = blockIdx.x, h = threadIdx.x;
  __shared__ float sb[128], s2ml[128];
  sb[h] = s[b*128+h];
  __syncthreads();
  s2s[b*128+h] = ftanh(dots(A_w + h*128, sb) + A_b[h]);
  float sm = ftanh(dots(C_w + h*128, sb) + C_b[h]);
  s2m_g[b*128+h] = sm; s2ml[h] = sm;
  for(int k=0;k<4;k++){
    float d = ftanh(dots(mB_w + (size_t)(k*128+h)*128, sb) + mB_b[k*128+h]);
    w2[b*512 + k*128 + h] = d * mC_w[k*128+h];
  }
  __syncthreads();
  gmB_lin[b*128+h] = dots(gmB_w + h*128, s2ml) + gmB_b[h];
}

// ------------- merged attention: mA logits + linearized mD via weighted node-sum --
__global__ __launch_bounds__(512,4) void k_att(const float* __restrict__ v, const float* __restrict__ w2,
                      const float* __restrict__ mA_w, const float* __restrict__ mA_b,
                      const float* __restrict__ mC_b,
                      const float* __restrict__ mD_w, const float* __restrict__ mD_b,
                      float* __restrict__ asum, float* __restrict__ m2s_num){
  int g = blockIdx.x / CH_PER_G, chunk = blockIdx.x % CH_PER_G;
  int start = g*NODES_PER_G, end = (g==NB-1)? N_NODES : start+NODES_PER_G;
  int node0 = start + chunk*16;
  int cnt = end - node0; if(cnt<=0) return; if(cnt>16) cnt=16;
  int t = threadIdx.x; int k = t>>7; int wv = t>>6;
  __shared__ float vl[16][128];
  __shared__ float red[16][8];
  __shared__ float ael[16][4];
  __shared__ float yv[4][128];     // y[k] = sum_n ael[n][k] * v_n
  __shared__ float aes[4];         // sum_n ael[n][k]
  for(int i=t;i<16*32;i+=512){
    int n=i>>5, c=i&31;
    float4 val = (n<cnt) ? ((const float4*)(v + (size_t)(node0+n)*128))[c]
                         : make_float4(0.f,0.f,0.f,0.f);
    ((float4*)vl[n])[c] = val;
  }
  __syncthreads();
  const float4* wA = (const float4*)(mA_w + (size_t)t*128);
  float accA[16];
#pragma unroll
  for(int n=0;n<16;n++) accA[n]=0.f;
  for(int kc=0;kc<32;kc++){
    float4 wa = wA[kc];
#pragma unroll
    for(int n=0;n<16;n++){
      float4 xv = ((const float4*)vl[n])[kc];
      accA[n]=fmaf(wa.x,xv.x,accA[n]); accA[n]=fmaf(wa.y,xv.y,accA[n]);
      accA[n]=fmaf(wa.z,xv.z,accA[n]); accA[n]=fmaf(wa.w,xv.w,accA[n]);
    }
  }
  float biasA = mA_b[t];
  float wc    = w2[g*512+t];
  for(int n=0;n<16;n++){
    float d = ftanh(accA[n] + biasA) * wc;
    for(int o=32;o>0;o>>=1) d += __shfl_down(d, o);
    if((t&63)==0) red[n][wv] = d;
  }
  __syncthreads();
  if(t<64){
    int n=t>>2, kk=t&3;
    float ae=0.f;
    if(n<cnt){
      ae = __expf(red[n][2*kk] + red[n][2*kk+1] + mC_b[kk]);
      atomicAdd(&asum[g*4+kk], ae);
    }
    ael[n][kk]=ae;
  }
  __syncthreads();
  {
    int c = t & 127;
    float y = 0.f;
#pragma unroll
    for(int n=0;n<16;n++) y = fmaf(ael[n][k], vl[n][c], y);
    yv[k][c] = y;
    if(t<4){
      float a0=0.f;
#pragma unroll
      for(int n=0;n<16;n++) a0 += ael[n][t];
      aes[t]=a0;
    }
  }
  __syncthreads();
  float outv = dots(mD_w + (size_t)t*128, yv[k]) + mD_b[t]*aes[k];
  atomicAdd(&m2s_num[(size_t)g*512 + t], outv);
}

// ---------------- edge message + scatter-add into nbuf (dst-range filtered) -------
__global__ __launch_bounds__(128,4) void k_edge(const float* __restrict__ v, const float* __restrict__ e,
                       const int* __restrict__ src, const int* __restrict__ dst,
                       const float* K_w, const float* K_b,
                       float* __restrict__ nbuf, int lo, int hi){
  int h = threadIdx.x;
  int e0 = blockIdx.x * 16;
  __shared__ float el[16][16];
  __shared__ int sl[16], dl[16];
  for(int i=h;i<256;i+=128){ int ee=i>>4, c=i&15; el[ee][c]=e[(size_t)(e0+ee)*16+c]; }
  if(h<16){ sl[h]=src[e0+h]; dl[h]=dst[e0+h]; }
  float4 kw[4];
  { const float4* q=(const float4*)(K_w + h*16);
    kw[0]=q[0]; kw[1]=q[1]; kw[2]=q[2]; kw[3]=q[3]; }
  float kb = K_b[h];
  __syncthreads();
  for(int j=0;j<16;j++){
    int dj = dl[j];
    if(dj < lo || dj >= hi) continue;
    int sj = sl[j]; if((u32)sj >= (u32)N_NODES) sj = 0;
    float kv=kb;
#pragma unroll
    for(int i=0;i<4;i++){
      float4 t = kw[i];
      kv = fmaf(t.x, el[j][4*i+0], kv);
      kv = fmaf(t.y, el[j][4*i+1], kv);
      kv = fmaf(t.z, el[j][4*i+2], kv);
      kv = fmaf(t.w, el[j][4*i+3], kv);
    }
    float vs = v[(size_t)sj*128+h];
    float val = kv*vs; val = (val>0.f)? val : 0.1f*val;
    atomicAdd(&nbuf[(size_t)(dj-lo)*128+h], val);
  }
}

// ---------------- fused node pipeline via split-bf16 MFMA -------------------------
// 16 nodes/block, 4 waves. MFMA 16x16x32 bf16 layouts (guide §3 / m89):
//   A frag : lane l, elem b -> X[l&15][(l>>4)*8 + b]           (node-major)
//   B frag : lane l, elem b -> W[l&15 + 16*ht][(l>>4)*8 + b]   (row-major weight = B^T)
//   D      : lane l, reg  r -> node=(l>>4)*4+r, h=l&15
// fp32 accuracy via 3-term split: xh*wh + xh*wl + xl*wh  (drop xl*wl ~2^-16)
__global__ __launch_bounds__(256,2) void k_node(
    const float* __restrict__ v, const int* __restrict__ graph_id,
    const u16* __restrict__ whi, const u16* __restrict__ wlo,
    const float* __restrict__ E_b, const float* __restrict__ gmA_b,
    const float* __restrict__ gmB_lin, const float* __restrict__ s2m_g,
    const float* __restrict__ bih, const float* __restrict__ bhh,
    const float* __restrict__ nbuf, float* __restrict__ out, int lo_){
  int t = threadIdx.x;
  int nl0 = blockIdx.x*16;
  int node0 = lo_ + nl0;
  int lane = t & 63, wv = t>>6;
  int lr = lane & 15, lg = lane >> 4;
  int koff = lg*8;

  // XH/XL rows padded to 264 u16 (528 B): A-frag ds_read_b128 lands 2-way on banks (free)
  __shared__ u16 XH[16][264];
  __shared__ u16 XL[16][264];
  __shared__ float ML[16][128];      // m2m -> hgate (fp32)
  __shared__ float scr[3][16][128];  // gh gates (+bias) from waves 2,3
  __shared__ int gid[16];

  // ---- stage + split-convert X = [sve | v] -> bf16 hi/lo
  for(int i=t; i<16*64; i+=256){
    int n = i>>6, c4 = i&63;
    float4 val = (c4<32) ? ((const float4*)(nbuf + (size_t)(nl0+n)*128))[c4]
                         : ((const float4*)(v + (size_t)(node0+n)*128))[c4-32];
    int c = c4<<2;
    u32 h01,l01,h23,l23;
    cvt2(val.x, val.y, h01, l01);
    cvt2(val.z, val.w, h23, l23);
    *(uint2*)&XH[n][c] = make_uint2(h01, h23);
    *(uint2*)&XL[n][c] = make_uint2(l01, l23);
  }
  if(t<16) gid[t] = graph_id[node0+t] & 63;
  __syncthreads();

  // ---- phase 1: m2m = leaky(E_w @ [sve; v] + E_b)   K=256, 8 h-tiles / 4 waves
  {
    f32x4 acc[2] = {{0.f,0.f,0.f,0.f},{0.f,0.f,0.f,0.f}};
    int hrow = (wv*2)*16 + lr;
    const u16* b0h = whi + (size_t)hrow*256 + koff;
    const u16* b0l = wlo + (size_t)hrow*256 + koff;
    const u16* b1h = b0h + 16*256;
    const u16* b1l = b0l + 16*256;
    const u16* pah = &XH[lr][koff];
    const u16* pal = &XL[lr][koff];
#pragma unroll
    for(int ks=0; ks<8; ks++){
      bf16x8 ah  = *(const bf16x8*)(pah + ks*32);
      bf16x8 al  = *(const bf16x8*)(pal + ks*32);
      bf16x8 w0h = *(const bf16x8*)(b0h + ks*32);
      bf16x8 w0l = *(const bf16x8*)(b0l + ks*32);
      bf16x8 w1h = *(const bf16x8*)(b1h + ks*32);
      bf16x8 w1l = *(const bf16x8*)(b1l + ks*32);
      acc[0] = MFMA16(ah, w0h, acc[0], 0,0,0);
      acc[0] = MFMA16(ah, w0l, acc[0], 0,0,0);
      acc[0] = MFMA16(al, w0h, acc[0], 0,0,0);
      acc[1] = MFMA16(ah, w1h, acc[1], 0,0,0);
      acc[1] = MFMA16(ah, w1l, acc[1], 0,0,0);
      acc[1] = MFMA16(al, w1h, acc[1], 0,0,0);
    }
    __syncthreads();   // all reads of XH/XL[0:256] done before overwrite
#pragma unroll
    for(int tt=0; tt<2; tt++){
      int hcol = (wv*2+tt)*16 + lr;
      float eb = E_b[hcol];
#pragma unroll
      for(int r=0; r<4; r++){
        int n = lg*4 + r;
        float m = acc[tt][r] + eb;
        m = (m>0.f)? m : 0.1f*m;
        ML[n][hcol] = m;
        u32 mb = __float_as_uint(m);
        u16 mh = (u16)(mb>>16);
        XH[n][hcol] = mh;
        float mlr = m - __uint_as_float((u32)mh<<16);
        XL[n][hcol] = (u16)(__float_as_uint(mlr)>>16);
      }
    }
    __syncthreads();
  }

  // ---- phase 2: z = sigmoid(gmA@m2m + gmA_b + gmB_lin); hgate = z*s2m + (1-z)*m2m
  {
    const u16* gah = whi + 32768;
    const u16* gal = wlo + 32768;
    f32x4 acc[2] = {{0.f,0.f,0.f,0.f},{0.f,0.f,0.f,0.f}};
    int hrow = (wv*2)*16 + lr;
    const u16* b0h = gah + (size_t)hrow*128 + koff;
    const u16* b0l = gal + (size_t)hrow*128 + koff;
    const u16* b1h = b0h + 16*128;
    const u16* b1l = b0l + 16*128;
    const u16* pah = &XH[lr][koff];
    const u16* pal = &XL[lr][koff];
#pragma unroll
    for(int ks=0; ks<4; ks++){
      bf16x8 ah  = *(const bf16x8*)(pah + ks*32);
      bf16x8 al  = *(const bf16x8*)(pal + ks*32);
      bf16x8 w0h = *(const bf16x8*)(b0h + ks*32);
      bf16x8 w0l = *(const bf16x8*)(b0l + ks*32);
      bf16x8 w1h = *(const bf16x8*)(b1h + ks*32);
      bf16x8 w1l = *(const bf16x8*)(b1l + ks*32);
      acc[0] = MFMA16(ah, w0h, acc[0], 0,0,0);
      acc[0] = MFMA16(ah, w0l, acc[0], 0,0,0);
      acc[0] = MFMA16(al, w0h, acc[0], 0,0,0);
      acc[1] = MFMA16(ah, w1h, acc[1], 0,0,0);
      acc[1] = MFMA16(ah, w1l, acc[1], 0,0,0);
      acc[1] = MFMA16(al, w1h, acc[1], 0,0,0);
    }
    __syncthreads();
#pragma unroll
    for(int tt=0; tt<2; tt++){
      int hcol = (wv*2+tt)*16 + lr;
      float ab = gmA_b[hcol];
#pragma unroll
      for(int r=0; r<4; r++){
        int n = lg*4 + r;
        int g = gid[n];
        float z = sigmoidf_(acc[tt][r] + ab + gmB_lin[g*128+hcol]);
        float hg = z*s2m_g[g*128+hcol] + (1.f-z)*ML[n][hcol];
        ML[n][hcol] = hg;
        u32 mb = __float_as_uint(hg);
        u16 mh = (u16)(mb>>16);
        XH[n][hcol] = mh;
        float mlr = hg - __uint_as_float((u32)mh<<16);
        XL[n][hcol] = (u16)(__float_as_uint(mlr)>>16);
      }
    }
    __syncthreads();
  }

  // ---- phase 3: GRU. waves 0,1: gi = wih@v ; waves 2,3: gh = whh@hgate
  {
    const u16* wbh; const u16* wbl; int xoff;
    if(wv < 2){ wbh = whi + 49152; wbl = wlo + 49152; xoff = 128; }
    else      { wbh = whi + 98304; wbl = wlo + 98304; xoff = 0;   }
    int wp = wv & 1;
    f32x4 acc[3][4];
#pragma unroll
    for(int j=0;j<3;j++)
#pragma unroll
      for(int tt=0;tt<4;tt++){ f32x4 z4 = {0.f,0.f,0.f,0.f}; acc[j][tt]=z4; }
    const u16* pah = &XH[lr][xoff + koff];
    const u16* pal = &XL[lr][xoff + koff];
#pragma unroll
    for(int ks=0; ks<4; ks++){
      bf16x8 ah = *(const bf16x8*)(pah + ks*32);
      bf16x8 al = *(const bf16x8*)(pal + ks*32);
#pragma unroll
      for(int j=0;j<3;j++){
#pragma unroll
        for(int tt=0;tt<4;tt++){
          int row = j*128 + (wp*4+tt)*16 + lr;
          bf16x8 wh_ = *(const bf16x8*)(wbh + (size_t)row*128 + koff + ks*32);
          bf16x8 wl_ = *(const bf16x8*)(wbl + (size_t)row*128 + koff + ks*32);
          acc[j][tt] = MFMA16(ah, wh_, acc[j][tt], 0,0,0);
          acc[j][tt] = MFMA16(ah, wl_, acc[j][tt], 0,0,0);
          acc[j][tt] = MFMA16(al, wh_, acc[j][tt], 0,0,0);
        }
      }
    }
    if(wv >= 2){
#pragma unroll
      for(int j=0;j<3;j++){
#pragma unroll
        for(int tt=0;tt<4;tt++){
          int hh = (wp*4+tt)*16 + lr;
          float bb = bhh[j*128+hh];
#pragma unroll
          for(int r=0;r<4;r++) scr[j][lg*4+r][hh] = acc[j][tt][r] + bb;
        }
      }
    }
    __syncthreads();
    if(wv < 2){
#pragma unroll
      for(int tt=0;tt<4;tt++){
        int hh = (wp*4+tt)*16 + lr;
        float b0 = bih[hh], b1 = bih[128+hh], b2 = bih[256+hh];
#pragma unroll
        for(int r=0;r<4;r++){
          int n = lg*4 + r;
          float gi0 = acc[0][tt][r] + b0;
          float gi1 = acc[1][tt][r] + b1;
          float gi2 = acc[2][tt][r] + b2;
          float rr = sigmoidf_(gi0 + scr[0][n][hh]);
          float zz = sigmoidf_(gi1 + scr[1][n][hh]);
          float nn = ftanh(gi2 + rr*scr[2][n][hh]);
          float hg = ML[n][hh];
          out[(size_t)(node0+n)*128 + hh] = (1.f-zz)*nn + zz*hg;
        }
      }
    }
  }
}

// ---------------- supernode finish: m2s, gate, GRU -> update_s ---------------------
__global__ __launch_bounds__(128,4) void k_sup2(const float* __restrict__ s,
                       const float* __restrict__ m2s_num, const float* __restrict__ asum,
                       const float* __restrict__ s2s,
                       const float* B_w, const float* B_b,
                       const float* gsA_w, const float* gsA_b,
                       const float* gsB_w, const float* gsB_b,
                       const float* wih, const float* bih, const float* whh, const float* bhh,
                       float* __restrict__ out){
  int b=blockIdx.x, h=threadIdx.x;
  __shared__ float m2si[512], m2sl[128], s2sl[128], sl[128], hgl[128];
  for(int j=0;j<4;j++){ int kh=h+j*128; m2si[kh] = m2s_num[b*512+kh] / asum[b*4 + (kh>>7)]; }
  s2sl[h]=s2s[b*128+h];
  sl[h]=s[b*128+h];
  __syncthreads();
  float acc = B_b[h];
  { const float4* q=(const float4*)(B_w + (size_t)h*512);
#pragma unroll 8
    for(int i=0;i<128;i++){
      float4 p=q[i]; int base=i*4;
      acc=fmaf(p.x,m2si[base+0],acc); acc=fmaf(p.y,m2si[base+1],acc);
      acc=fmaf(p.z,m2si[base+2],acc); acc=fmaf(p.w,m2si[base+3],acc);
    }
  }
  float m2sv = ftanh(acc);
  m2sl[h]=m2sv;
  __syncthreads();
  float zacc = dots(gsA_w+(size_t)h*128, s2sl) + gsA_b[h];
  zacc      += dots(gsB_w+(size_t)h*128, m2sl) + gsB_b[h];
  float z = sigmoidf_(zacc);
  float hg = z*m2sl[h] + (1.f-z)*s2sl[h];
  hgl[h]=hg;
  __syncthreads();
  float gi[3], gh[3];
  for(int j=0;j<3;j++){
    gi[j]=dots(wih+(size_t)(h+j*128)*128, sl)+bih[h+j*128];
    gh[j]=dots(whh+(size_t)(h+j*128)*128, hgl)+bhh[h+j*128];
  }
  float r=sigmoidf_(gi[0]+gh[0]), z2=sigmoidf_(gi[1]+gh[1]);
  float nn=ftanh(gi[2]+r*gh[2]);
  out[(size_t)N_NODES*128 + b*128 + h] = (1.f-z2)*nn + z2*hg;
}

extern "C" void kernel_launch(void* const* d_in, const int* in_sizes, int n_in,
                              void* d_out, int out_size, void* d_ws, size_t ws_size,
                              hipStream_t stream){
  const float* v   = (const float*)d_in[0];
  const float* e   = (const float*)d_in[1];
  const float* s   = (const float*)d_in[2];
  const int* src  = (const int*)d_in[3];
  const int* dst  = (const int*)d_in[4];
  const int* graph_id = (const int*)d_in[5];
  const float* A_w=(const float*)d_in[6];  const float* A_b=(const float*)d_in[7];
  const float* B_w=(const float*)d_in[8];  const float* B_b=(const float*)d_in[9];
  const float* C_w=(const float*)d_in[10]; const float* C_b=(const float*)d_in[11];
  const float* E_w=(const float*)d_in[12]; const float* E_b=(const float*)d_in[13];
  const float* K_w=(const float*)d_in[14]; const float* K_b=(const float*)d_in[15];
  const float* mA_w=(const float*)d_in[16]; const float* mA_b=(const float*)d_in[17];
  const float* mB_w=(const float*)d_in[18]; const float* mB_b=(const float*)d_in[19];
  const float* mC_w=(const float*)d_in[20]; const float* mC_b=(const float*)d_in[21];
  const float* mD_w=(const float*)d_in[22]; const float* mD_b=(const float*)d_in[23];
  const float* gmA_w=(const float*)d_in[24]; const float* gmA_b=(const float*)d_in[25];
  const float* gmB_w=(const float*)d_in[26]; const float* gmB_b=(const float*)d_in[27];
  const float* gm_wih=(const float*)d_in[28]; const float* gm_bih=(const float*)d_in[29];
  const float* gm_whh=(const float*)d_in[30]; const float* gm_bhh=(const float*)d_in[31];
  const float* gsA_w=(const float*)d_in[32]; const float* gsA_b=(const float*)d_in[33];
  const float* gsB_w=(const float*)d_in[34]; const float* gsB_b=(const float*)d_in[35];
  const float* gs_wih=(const float*)d_in[36]; const float* gs_bih=(const float*)d_in[37];
  const float* gs_whh=(const float*)d_in[38]; const float* gs_bhh=(const float*)d_in[39];

  float* ws = (float*)d_ws;
  float* asum    = ws;                  // 256
  float* m2s_num = asum + 256;          // 32768
  float* s2s     = m2s_num + 32768;     // 8192
  float* s2m_g   = s2s + 8192;          // 8192
  float* gmB_lin = s2m_g + 8192;        // 8192
  float* w2      = gmB_lin + 8192;      // 32768
  u16*   whi     = (u16*)(w2 + 32768);  // 147456 u16 (hi)
  u16*   wlo     = whi + 147456;        // 147456 u16 (lo)
  float* nbuf    = (float*)(wlo + 147456);
  const size_t small_f = 256 + 32768 + 8192*3 + 32768 + 147456;   // 237824 floats

  size_t ws_f = ws_size / 4;
  long avail = (ws_f > small_f) ? (long)(ws_f - small_f) : 0;
  long M = (avail / 128) & ~15L;
  if(M > N_NODES) M = N_NODES;
  if(M < 16) M = 16;

  hipMemsetAsync(asum, 0, (256 + 32768) * sizeof(float), stream);

  k_prep<<<576, 256, 0, stream>>>(E_w, gmA_w, gm_wih, gm_whh, whi, wlo);
  k_sup <<<NB, 128, 0, stream>>>(s, A_w,A_b, C_w,C_b, mB_w,mB_b,mC_w, gmB_w,gmB_b,
                                 s2s, s2m_g, w2, gmB_lin);
  k_att <<<NB*CH_PER_G, 512, 0, stream>>>(v, w2, mA_w, mA_b, mC_b, mD_w, mD_b,
                                          asum, m2s_num);
  k_sup2<<<NB, 128, 0, stream>>>(s, m2s_num, asum, s2s, B_w,B_b,
                                 gsA_w,gsA_b, gsB_w,gsB_b,
                                 gs_wih,gs_bih, gs_whh,gs_bhh, (float*)d_out);

  for(long lo = 0; lo < N_NODES; lo += M){
    long cnt = N_NODES - lo; if(cnt > M) cnt = M;
    int ilo = (int)lo, icnt = (int)cnt;
    hipMemsetAsync(nbuf, 0, (size_t)icnt*128*sizeof(float), stream);
    k_edge<<<N_EDGES/16, 128, 0, stream>>>(v, e, src, dst, K_w, K_b, nbuf, ilo, ilo+icnt);
    k_node<<<icnt/16, 256, 0, stream>>>(v, graph_id, whi, wlo, E_b, gmA_b,
                                        gmB_lin, s2m_g, gm_bih, gm_bhh,
                                        nbuf, (float*)d_out, ilo);
  }
}

// Round 3
// 1649.335 us; speedup vs baseline: 1.2758x; 1.0466x over previous
//
#include <hip/hip_runtime.h>
#include <math.h>

typedef unsigned int u32;
typedef unsigned short u16;

#define N_NODES 100000
#define N_EDGES 1000000
#define NB      64
#define NODES_PER_G 1562   // N // B; graph 63 holds 1594
#define CH_PER_G 100       // ceil(1594/16)

typedef __attribute__((ext_vector_type(8))) short bf16x8;   // 8 bf16 = 4 VGPR
typedef __attribute__((ext_vector_type(4))) float f32x4;
#define MFMA16 __builtin_amdgcn_mfma_f32_16x16x32_bf16

__device__ __forceinline__ float sigmoidf_(float x){ return 1.f/(1.f+__expf(-x)); }
__device__ __forceinline__ float ftanh(float x){
  float e = __expf(-2.f*fabsf(x));
  float t = (1.f - e)/(1.f + e);
  return copysignf(t, x);
}

// streaming 128-dot: weights from global (L2-hot), x from LDS
__device__ __forceinline__ float dots(const float* w, const float* x){
  const float4* w4 = (const float4*)w;
  float a = 0.f;
#pragma unroll 8
  for(int i=0;i<32;i++){
    float4 t = w4[i];
    a = fmaf(t.x, x[4*i+0], a);
    a = fmaf(t.y, x[4*i+1], a);
    a = fmaf(t.z, x[4*i+2], a);
    a = fmaf(t.w, x[4*i+3], a);
  }
  return a;
}

// Dekker split: x = hi + lo, both bf16 (truncation); residual ~2^-16 relative
__device__ __forceinline__ void cvt2(float a, float b, u32 &hi, u32 &lo){
  u32 ab = __float_as_uint(a), bb = __float_as_uint(b);
  hi = (ab>>16) | (bb & 0xffff0000u);
  float ar = a - __uint_as_float(ab & 0xffff0000u);
  float br = b - __uint_as_float(bb & 0xffff0000u);
  lo = (__float_as_uint(ar)>>16) | (__float_as_uint(br) & 0xffff0000u);
}

// ------------- one-time weight split: fp32 -> bf16 hi/lo arrays in ws -------------
// flat u16 index: [E_w 32768][gmA_w 16384][gm_wih 49152][gm_whh 49152][mA_w 65536]
__global__ __launch_bounds__(256) void k_prep(const float* __restrict__ ew,
                    const float* __restrict__ ga,
                    const float* __restrict__ wih,
                    const float* __restrict__ whh,
                    const float* __restrict__ maw,
                    u16* __restrict__ hi, u16* __restrict__ lo){
  int i = blockIdx.x*256 + threadIdx.x;
  float x;
  if(i < 32768) x = ew[i];
  else if(i < 49152) x = ga[i-32768];
  else if(i < 98304) x = wih[i-49152];
  else if(i < 147456) x = whh[i-98304];
  else if(i < 212992) x = maw[i-147456];
  else return;
  u32 b = __float_as_uint(x);
  u16 h = (u16)(b>>16);
  float hf = __uint_as_float((u32)h<<16);
  float l = x - hf;
  hi[i] = h;
  lo[i] = (u16)(__float_as_uint(l)>>16);
}

// ---------------- per-graph precompute: s2s, s2m, w2(=dsup*mC), gmB_lin ----------
__global__ __launch_bounds__(128,4) void k_sup(const float* __restrict__ s,
                      const float* A_w, const float* A_b,
                      const float* C_w, const float* C_b,
                      const float* mB_w, const float* mB_b, const float* mC_w,
                      const float* gmB_w, const float* gmB_b,
                      float* s2s, float* s2m_g, float* w2, float* gmB_lin){
  int b = blockIdx.x, h = threadIdx.x;
  __shared__ float sb[128], s2ml[128];
  sb[h] = s[b*128+h];
  __syncthreads();
  s2s[b*128+h] = ftanh(dots(A_w + h*128, sb) + A_b[h]);
  float sm = ftanh(dots(C_w + h*128, sb) + C_b[h]);
  s2m_g[b*128+h] = sm; s2ml[h] = sm;
  for(int k=0;k<4;k++){
    float d = ftanh(dots(mB_w + (size_t)(k*128+h)*128, sb) + mB_b[k*128+h]);
    w2[b*512 + k*128 + h] = d * mC_w[k*128+h];
  }
  __syncthreads();
  gmB_lin[b*128+h] = dots(gmB_w + h*128, s2ml) + gmB_b[h];
}

// ------------- attention via split-bf16 MFMA: logits + linearized mD --------------
// 256 thr / 4 waves; wave wv owns head wv. MFMA D: node=(lane>>4)*4+r, col tile*16+(lane&15).
// logit[n][k] = sum_col tanh(mA@v + mA_b)*w2 ; reduce over col = 8 tiles/lane + 4x shfl_xor.
__global__ __launch_bounds__(256,4) void k_att(const float* __restrict__ v,
                      const float* __restrict__ w2,
                      const u16* __restrict__ mAhi, const u16* __restrict__ mAlo,
                      const float* __restrict__ mA_b,
                      const float* __restrict__ mC_b,
                      const float* __restrict__ mD_w, const float* __restrict__ mD_b,
                      float* __restrict__ asum, float* __restrict__ m2s_num){
  int g = blockIdx.x / CH_PER_G, chunk = blockIdx.x % CH_PER_G;
  int start = g*NODES_PER_G, end = (g==NB-1)? N_NODES : start+NODES_PER_G;
  int node0 = start + chunk*16;
  int cnt = end - node0; if(cnt<=0) return; if(cnt>16) cnt=16;
  int t = threadIdx.x;
  int lane = t & 63, wv = t>>6;      // wv = head
  int lr = lane & 15, lg = lane >> 4;
  int koff = lg*8;

  __shared__ float vl[16][128];
  __shared__ u16 XH[16][136], XL[16][136];   // 272B row stride: mod-32-bank offset 4/lane
  __shared__ float ael[16][4];
  __shared__ float yv[4][128];
  __shared__ float aes[4];
  __shared__ float wl2[512], bA[512];

  for(int i=t;i<16*32;i+=256){
    int n=i>>5, c=i&31;
    float4 val = (n<cnt) ? ((const float4*)(v + (size_t)(node0+n)*128))[c]
                         : make_float4(0.f,0.f,0.f,0.f);
    ((float4*)vl[n])[c] = val;
    int cc = c<<2;
    u32 h01,l01,h23,l23;
    cvt2(val.x,val.y,h01,l01); cvt2(val.z,val.w,h23,l23);
    *(uint2*)&XH[n][cc] = make_uint2(h01,h23);
    *(uint2*)&XL[n][cc] = make_uint2(l01,l23);
  }
  for(int i=t;i<512;i+=256){ wl2[i]=w2[g*512+i]; bA[i]=mA_b[i]; }
  __syncthreads();

  // ---- logits: 8 col-tiles per head, K=128, 3-term split
  float sr0=0.f, sr1=0.f, sr2=0.f, sr3=0.f;
  const u16* pah = &XH[lr][koff];
  const u16* pal = &XL[lr][koff];
#pragma unroll
  for(int tt=0; tt<8; tt++){
    f32x4 acc = {0.f,0.f,0.f,0.f};
    int row = wv*128 + tt*16 + lr;
    const u16* bh  = mAhi + (size_t)row*128 + koff;
    const u16* bl_ = mAlo + (size_t)row*128 + koff;
#pragma unroll
    for(int ks=0; ks<4; ks++){
      bf16x8 ah  = *(const bf16x8*)(pah + ks*32);
      bf16x8 al  = *(const bf16x8*)(pal + ks*32);
      bf16x8 wh_ = *(const bf16x8*)(bh  + ks*32);
      bf16x8 wl_ = *(const bf16x8*)(bl_ + ks*32);
      acc = MFMA16(ah, wh_, acc, 0,0,0);
      acc = MFMA16(ah, wl_, acc, 0,0,0);
      acc = MFMA16(al, wh_, acc, 0,0,0);
    }
    float bb = bA[row], ww = wl2[row];
    sr0 += ftanh(acc[0]+bb)*ww;
    sr1 += ftanh(acc[1]+bb)*ww;
    sr2 += ftanh(acc[2]+bb)*ww;
    sr3 += ftanh(acc[3]+bb)*ww;
  }
  // reduce over the 16 col-lanes (same lg group)
#pragma unroll
  for(int m=1;m<16;m<<=1){
    sr0 += __shfl_xor(sr0, m, 64);
    sr1 += __shfl_xor(sr1, m, 64);
    sr2 += __shfl_xor(sr2, m, 64);
    sr3 += __shfl_xor(sr3, m, 64);
  }
  if(lr==0){
    float cb = mC_b[wv], la = 0.f;
    float a0 = (lg*4+0<cnt)? __expf(sr0+cb) : 0.f; ael[lg*4+0][wv]=a0; la+=a0;
    float a1 = (lg*4+1<cnt)? __expf(sr1+cb) : 0.f; ael[lg*4+1][wv]=a1; la+=a1;
    float a2 = (lg*4+2<cnt)? __expf(sr2+cb) : 0.f; ael[lg*4+2][wv]=a2; la+=a2;
    float a3 = (lg*4+3<cnt)? __expf(sr3+cb) : 0.f; ael[lg*4+3][wv]=a3; la+=a3;
    atomicAdd(&asum[g*4+wv], la);
  }
  __syncthreads();

  // ---- y[k] = sum_n ael[n][k]*v_n ; aes[k] = sum_n ael[n][k]
  {
    int c = t & 127, k0 = t>>7;       // handle heads k0 and k0+2
    float y0=0.f, y1=0.f;
#pragma unroll
    for(int n=0;n<16;n++){
      y0 = fmaf(ael[n][k0],   vl[n][c], y0);
      y1 = fmaf(ael[n][k0+2], vl[n][c], y1);
    }
    yv[k0][c]=y0; yv[k0+2][c]=y1;
    if(t<4){
      float a0=0.f;
#pragma unroll
      for(int n=0;n<16;n++) a0 += ael[n][t];
      aes[t]=a0;
    }
  }
  __syncthreads();

  // ---- mD matvec on y (2 rows/thread)
#pragma unroll
  for(int j=0;j<2;j++){
    int kh = t + j*256;
    int k = kh>>7;
    float outv = dots(mD_w + (size_t)kh*128, yv[k]) + mD_b[kh]*aes[k];
    atomicAdd(&m2s_num[(size_t)g*512 + kh], outv);
  }
}

// ---------------- edge message + scatter-add into nbuf (dst-range filtered) -------
__global__ __launch_bounds__(128,4) void k_edge(const float* __restrict__ v, const float* __restrict__ e,
                       const int* __restrict__ src, const int* __restrict__ dst,
                       const float* K_w, const float* K_b,
                       float* __restrict__ nbuf, int lo, int hi){
  int h = threadIdx.x;
  int e0 = blockIdx.x * 16;
  __shared__ float el[16][16];
  __shared__ int sl[16], dl[16];
  for(int i=h;i<256;i+=128){ int ee=i>>4, c=i&15; el[ee][c]=e[(size_t)(e0+ee)*16+c]; }
  if(h<16){ sl[h]=src[e0+h]; dl[h]=dst[e0+h]; }
  float4 kw[4];
  { const float4* q=(const float4*)(K_w + h*16);
    kw[0]=q[0]; kw[1]=q[1]; kw[2]=q[2]; kw[3]=q[3]; }
  float kb = K_b[h];
  __syncthreads();
  for(int j=0;j<16;j++){
    int dj = dl[j];
    if(dj < lo || dj >= hi) continue;
    int sj = sl[j]; if((u32)sj >= (u32)N_NODES) sj = 0;
    float kv=kb;
#pragma unroll
    for(int i=0;i<4;i++){
      float4 t = kw[i];
      kv = fmaf(t.x, el[j][4*i+0], kv);
      kv = fmaf(t.y, el[j][4*i+1], kv);
      kv = fmaf(t.z, el[j][4*i+2], kv);
      kv = fmaf(t.w, el[j][4*i+3], kv);
    }
    float vs = v[(size_t)sj*128+h];
    float val = kv*vs; val = (val>0.f)? val : 0.1f*val;
    atomicAdd(&nbuf[(size_t)(dj-lo)*128+h], val);
  }
}

// ---------------- fused node pipeline via split-bf16 MFMA -------------------------
// 16 nodes/block, 4 waves. MFMA 16x16x32 bf16 layouts (guide §3 / m89):
//   A frag : lane l, elem b -> X[l&15][(l>>4)*8 + b]           (node-major)
//   B frag : lane l, elem b -> W[l&15 + 16*ht][(l>>4)*8 + b]   (row-major weight = B^T)
//   D      : lane l, reg  r -> node=(l>>4)*4+r, h=l&15
// fp32 accuracy via 3-term split: xh*wh + xh*wl + xl*wh  (drop xl*wl ~2^-16)
__global__ __launch_bounds__(256,2) void k_node(
    const float* __restrict__ v, const int* __restrict__ graph_id,
    const u16* __restrict__ whi, const u16* __restrict__ wlo,
    const float* __restrict__ E_b, const float* __restrict__ gmA_b,
    const float* __restrict__ gmB_lin, const float* __restrict__ s2m_g,
    const float* __restrict__ bih, const float* __restrict__ bhh,
    const float* __restrict__ nbuf, float* __restrict__ out, int lo_){
  int t = threadIdx.x;
  int nl0 = blockIdx.x*16;
  int node0 = lo_ + nl0;
  int lane = t & 63, wv = t>>6;
  int lr = lane & 15, lg = lane >> 4;
  int koff = lg*8;

  __shared__ u16 XH[16][264];
  __shared__ u16 XL[16][264];
  __shared__ float ML[16][128];      // m2m -> hgate (fp32)
  __shared__ float scr[3][16][128];  // gh gates (+bias) from waves 2,3
  __shared__ int gid[16];

  // ---- stage + split-convert X = [sve | v] -> bf16 hi/lo
  for(int i=t; i<16*64; i+=256){
    int n = i>>6, c4 = i&63;
    float4 val = (c4<32) ? ((const float4*)(nbuf + (size_t)(nl0+n)*128))[c4]
                         : ((const float4*)(v + (size_t)(node0+n)*128))[c4-32];
    int c = c4<<2;
    u32 h01,l01,h23,l23;
    cvt2(val.x, val.y, h01, l01);
    cvt2(val.z, val.w, h23, l23);
    *(uint2*)&XH[n][c] = make_uint2(h01, h23);
    *(uint2*)&XL[n][c] = make_uint2(l01, l23);
  }
  if(t<16) gid[t] = graph_id[node0+t] & 63;
  __syncthreads();

  // ---- phase 1: m2m = leaky(E_w @ [sve; v] + E_b)   K=256, 8 h-tiles / 4 waves
  {
    f32x4 acc[2] = {{0.f,0.f,0.f,0.f},{0.f,0.f,0.f,0.f}};
    int hrow = (wv*2)*16 + lr;
    const u16* b0h = whi + (size_t)hrow*256 + koff;
    const u16* b0l = wlo + (size_t)hrow*256 + koff;
    const u16* b1h = b0h + 16*256;
    const u16* b1l = b0l + 16*256;
    const u16* pah = &XH[lr][koff];
    const u16* pal = &XL[lr][koff];
#pragma unroll
    for(int ks=0; ks<8; ks++){
      bf16x8 ah  = *(const bf16x8*)(pah + ks*32);
      bf16x8 al  = *(const bf16x8*)(pal + ks*32);
      bf16x8 w0h = *(const bf16x8*)(b0h + ks*32);
      bf16x8 w0l = *(const bf16x8*)(b0l + ks*32);
      bf16x8 w1h = *(const bf16x8*)(b1h + ks*32);
      bf16x8 w1l = *(const bf16x8*)(b1l + ks*32);
      acc[0] = MFMA16(ah, w0h, acc[0], 0,0,0);
      acc[0] = MFMA16(ah, w0l, acc[0], 0,0,0);
      acc[0] = MFMA16(al, w0h, acc[0], 0,0,0);
      acc[1] = MFMA16(ah, w1h, acc[1], 0,0,0);
      acc[1] = MFMA16(ah, w1l, acc[1], 0,0,0);
      acc[1] = MFMA16(al, w1h, acc[1], 0,0,0);
    }
    __syncthreads();
#pragma unroll
    for(int tt=0; tt<2; tt++){
      int hcol = (wv*2+tt)*16 + lr;
      float eb = E_b[hcol];
#pragma unroll
      for(int r=0; r<4; r++){
        int n = lg*4 + r;
        float m = acc[tt][r] + eb;
        m = (m>0.f)? m : 0.1f*m;
        ML[n][hcol] = m;
        u32 mb = __float_as_uint(m);
        u16 mh = (u16)(mb>>16);
        XH[n][hcol] = mh;
        float mlr = m - __uint_as_float((u32)mh<<16);
        XL[n][hcol] = (u16)(__float_as_uint(mlr)>>16);
      }
    }
    __syncthreads();
  }

  // ---- phase 2: z = sigmoid(gmA@m2m + gmA_b + gmB_lin); hgate = z*s2m + (1-z)*m2m
  {
    const u16* gah = whi + 32768;
    const u16* gal = wlo + 32768;
    f32x4 acc[2] = {{0.f,0.f,0.f,0.f},{0.f,0.f,0.f,0.f}};
    int hrow = (wv*2)*16 + lr;
    const u16* b0h = gah + (size_t)hrow*128 + koff;
    const u16* b0l = gal + (size_t)hrow*128 + koff;
    const u16* b1h = b0h + 16*128;
    const u16* b1l = b0l + 16*128;
    const u16* pah = &XH[lr][koff];
    const u16* pal = &XL[lr][koff];
#pragma unroll
    for(int ks=0; ks<4; ks++){
      bf16x8 ah  = *(const bf16x8*)(pah + ks*32);
      bf16x8 al  = *(const bf16x8*)(pal + ks*32);
      bf16x8 w0h = *(const bf16x8*)(b0h + ks*32);
      bf16x8 w0l = *(const bf16x8*)(b0l + ks*32);
      bf16x8 w1h = *(const bf16x8*)(b1h + ks*32);
      bf16x8 w1l = *(const bf16x8*)(b1l + ks*32);
      acc[0] = MFMA16(ah, w0h, acc[0], 0,0,0);
      acc[0] = MFMA16(ah, w0l, acc[0], 0,0,0);
      acc[0] = MFMA16(al, w0h, acc[0], 0,0,0);
      acc[1] = MFMA16(ah, w1h, acc[1], 0,0,0);
      acc[1] = MFMA16(ah, w1l, acc[1], 0,0,0);
      acc[1] = MFMA16(al, w1h, acc[1], 0,0,0);
    }
    __syncthreads();
#pragma unroll
    for(int tt=0; tt<2; tt++){
      int hcol = (wv*2+tt)*16 + lr;
      float ab = gmA_b[hcol];
#pragma unroll
      for(int r=0; r<4; r++){
        int n = lg*4 + r;
        int g = gid[n];
        float z = sigmoidf_(acc[tt][r] + ab + gmB_lin[g*128+hcol]);
        float hg = z*s2m_g[g*128+hcol] + (1.f-z)*ML[n][hcol];
        ML[n][hcol] = hg;
        u32 mb = __float_as_uint(hg);
        u16 mh = (u16)(mb>>16);
        XH[n][hcol] = mh;
        float mlr = hg - __uint_as_float((u32)mh<<16);
        XL[n][hcol] = (u16)(__float_as_uint(mlr)>>16);
      }
    }
    __syncthreads();
  }

  // ---- phase 3: GRU. waves 0,1: gi = wih@v ; waves 2,3: gh = whh@hgate
  {
    const u16* wbh; const u16* wbl; int xoff;
    if(wv < 2){ wbh = whi + 49152; wbl = wlo + 49152; xoff = 128; }
    else      { wbh = whi + 98304; wbl = wlo + 98304; xoff = 0;   }
    int wp = wv & 1;
    f32x4 acc[3][4];
#pragma unroll
    for(int j=0;j<3;j++)
#pragma unroll
      for(int tt=0;tt<4;tt++){ f32x4 z4 = {0.f,0.f,0.f,0.f}; acc[j][tt]=z4; }
    const u16* pah = &XH[lr][xoff + koff];
    const u16* pal = &XL[lr][xoff + koff];
#pragma unroll
    for(int ks=0; ks<4; ks++){
      bf16x8 ah = *(const bf16x8*)(pah + ks*32);
      bf16x8 al = *(const bf16x8*)(pal + ks*32);
#pragma unroll
      for(int j=0;j<3;j++){
#pragma unroll
        for(int tt=0;tt<4;tt++){
          int row = j*128 + (wp*4+tt)*16 + lr;
          bf16x8 wh_ = *(const bf16x8*)(wbh + (size_t)row*128 + koff + ks*32);
          bf16x8 wl_ = *(const bf16x8*)(wbl + (size_t)row*128 + koff + ks*32);
          acc[j][tt] = MFMA16(ah, wh_, acc[j][tt], 0,0,0);
          acc[j][tt] = MFMA16(ah, wl_, acc[j][tt], 0,0,0);
          acc[j][tt] = MFMA16(al, wh_, acc[j][tt], 0,0,0);
        }
      }
    }
    if(wv >= 2){
#pragma unroll
      for(int j=0;j<3;j++){
#pragma unroll
        for(int tt=0;tt<4;tt++){
          int hh = (wp*4+tt)*16 + lr;
          float bb = bhh[j*128+hh];
#pragma unroll
          for(int r=0;r<4;r++) scr[j][lg*4+r][hh] = acc[j][tt][r] + bb;
        }
      }
    }
    __syncthreads();
    if(wv < 2){
#pragma unroll
      for(int tt=0;tt<4;tt++){
        int hh = (wp*4+tt)*16 + lr;
        float b0 = bih[hh], b1 = bih[128+hh], b2 = bih[256+hh];
#pragma unroll
        for(int r=0;r<4;r++){
          int n = lg*4 + r;
          float gi0 = acc[0][tt][r] + b0;
          float gi1 = acc[1][tt][r] + b1;
          float gi2 = acc[2][tt][r] + b2;
          float rr = sigmoidf_(gi0 + scr[0][n][hh]);
          float zz = sigmoidf_(gi1 + scr[1][n][hh]);
          float nn = ftanh(gi2 + rr*scr[2][n][hh]);
          float hg = ML[n][hh];
          out[(size_t)(node0+n)*128 + hh] = (1.f-zz)*nn + zz*hg;
        }
      }
    }
  }
}

// ---------------- supernode finish: m2s, gate, GRU -> update_s ---------------------
__global__ __launch_bounds__(128,4) void k_sup2(const float* __restrict__ s,
                       const float* __restrict__ m2s_num, const float* __restrict__ asum,
                       const float* __restrict__ s2s,
                       const float* B_w, const float* B_b,
                       const float* gsA_w, const float* gsA_b,
                       const float* gsB_w, const float* gsB_b,
                       const float* wih, const float* bih, const float* whh, const float* bhh,
                       float* __restrict__ out){
  int b=blockIdx.x, h=threadIdx.x;
  __shared__ float m2si[512], m2sl[128], s2sl[128], sl[128], hgl[128];
  for(int j=0;j<4;j++){ int kh=h+j*128; m2si[kh] = m2s_num[b*512+kh] / asum[b*4 + (kh>>7)]; }
  s2sl[h]=s2s[b*128+h];
  sl[h]=s[b*128+h];
  __syncthreads();
  float acc = B_b[h];
  { const float4* q=(const float4*)(B_w + (size_t)h*512);
#pragma unroll 8
    for(int i=0;i<128;i++){
      float4 p=q[i]; int base=i*4;
      acc=fmaf(p.x,m2si[base+0],acc); acc=fmaf(p.y,m2si[base+1],acc);
      acc=fmaf(p.z,m2si[base+2],acc); acc=fmaf(p.w,m2si[base+3],acc);
    }
  }
  float m2sv = ftanh(acc);
  m2sl[h]=m2sv;
  __syncthreads();
  float zacc = dots(gsA_w+(size_t)h*128, s2sl) + gsA_b[h];
  zacc      += dots(gsB_w+(size_t)h*128, m2sl) + gsB_b[h];
  float z = sigmoidf_(zacc);
  float hg = z*m2sl[h] + (1.f-z)*s2sl[h];
  hgl[h]=hg;
  __syncthreads();
  float gi[3], gh[3];
  for(int j=0;j<3;j++){
    gi[j]=dots(wih+(size_t)(h+j*128)*128, sl)+bih[h+j*128];
    gh[j]=dots(whh+(size_t)(h+j*128)*128, hgl)+bhh[h+j*128];
  }
  float r=sigmoidf_(gi[0]+gh[0]), z2=sigmoidf_(gi[1]+gh[1]);
  float nn=ftanh(gi[2]+r*gh[2]);
  out[(size_t)N_NODES*128 + b*128 + h] = (1.f-z2)*nn + z2*hg;
}

extern "C" void kernel_launch(void* const* d_in, const int* in_sizes, int n_in,
                              void* d_out, int out_size, void* d_ws, size_t ws_size,
                              hipStream_t stream){
  const float* v   = (const float*)d_in[0];
  const float* e   = (const float*)d_in[1];
  const float* s   = (const float*)d_in[2];
  const int* src  = (const int*)d_in[3];
  const int* dst  = (const int*)d_in[4];
  const int* graph_id = (const int*)d_in[5];
  const float* A_w=(const float*)d_in[6];  const float* A_b=(const float*)d_in[7];
  const float* B_w=(const float*)d_in[8];  const float* B_b=(const float*)d_in[9];
  const float* C_w=(const float*)d_in[10]; const float* C_b=(const float*)d_in[11];
  const float* E_w=(const float*)d_in[12]; const float* E_b=(const float*)d_in[13];
  const float* K_w=(const float*)d_in[14]; const float* K_b=(const float*)d_in[15];
  const float* mA_w=(const float*)d_in[16]; const float* mA_b=(const float*)d_in[17];
  const float* mB_w=(const float*)d_in[18]; const float* mB_b=(const float*)d_in[19];
  const float* mC_w=(const float*)d_in[20]; const float* mC_b=(const float*)d_in[21];
  const float* mD_w=(const float*)d_in[22]; const float* mD_b=(const float*)d_in[23];
  const float* gmA_w=(const float*)d_in[24]; const float* gmA_b=(const float*)d_in[25];
  const float* gmB_w=(const float*)d_in[26]; const float* gmB_b=(const float*)d_in[27];
  const float* gm_wih=(const float*)d_in[28]; const float* gm_bih=(const float*)d_in[29];
  const float* gm_whh=(const float*)d_in[30]; const float* gm_bhh=(const float*)d_in[31];
  const float* gsA_w=(const float*)d_in[32]; const float* gsA_b=(const float*)d_in[33];
  const float* gsB_w=(const float*)d_in[34]; const float* gsB_b=(const float*)d_in[35];
  const float* gs_wih=(const float*)d_in[36]; const float* gs_bih=(const float*)d_in[37];
  const float* gs_whh=(const float*)d_in[38]; const float* gs_bhh=(const float*)d_in[39];

  float* ws = (float*)d_ws;
  float* asum    = ws;                  // 256
  float* m2s_num = asum + 256;          // 32768
  float* s2s     = m2s_num + 32768;     // 8192
  float* s2m_g   = s2s + 8192;          // 8192
  float* gmB_lin = s2m_g + 8192;        // 8192
  float* w2      = gmB_lin + 8192;      // 32768
  u16*   whi     = (u16*)(w2 + 32768);  // 212992 u16 (hi)
  u16*   wlo     = whi + 212992;        // 212992 u16 (lo)
  float* nbuf    = (float*)(wlo + 212992);
  const size_t small_f = 256 + 32768 + 8192*3 + 32768 + 212992;   // 303360 floats

  size_t ws_f = ws_size / 4;
  long avail = (ws_f > small_f) ? (long)(ws_f - small_f) : 0;
  long M = (avail / 128) & ~15L;
  if(M > N_NODES) M = N_NODES;
  if(M < 16) M = 16;

  hipMemsetAsync(asum, 0, (256 + 32768) * sizeof(float), stream);

  k_prep<<<832, 256, 0, stream>>>(E_w, gmA_w, gm_wih, gm_whh, mA_w, whi, wlo);
  k_sup <<<NB, 128, 0, stream>>>(s, A_w,A_b, C_w,C_b, mB_w,mB_b,mC_w, gmB_w,gmB_b,
                                 s2s, s2m_g, w2, gmB_lin);
  k_att <<<NB*CH_PER_G, 256, 0, stream>>>(v, w2, whi + 147456, wlo + 147456,
                                          mA_b, mC_b, mD_w, mD_b, asum, m2s_num);
  k_sup2<<<NB, 128, 0, stream>>>(s, m2s_num, asum, s2s, B_w,B_b,
                                 gsA_w,gsA_b, gsB_w,gsB_b,
                                 gs_wih,gs_bih, gs_whh,gs_bhh, (float*)d_out);

  for(long lo = 0; lo < N_NODES; lo += M){
    long cnt = N_NODES - lo; if(cnt > M) cnt = M;
    int ilo = (int)lo, icnt = (int)cnt;
    hipMemsetAsync(nbuf, 0, (size_t)icnt*128*sizeof(float), stream);
    k_edge<<<N_EDGES/16, 128, 0, stream>>>(v, e, src, dst, K_w, K_b, nbuf, ilo, ilo+icnt);
    k_node<<<icnt/16, 256, 0, stream>>>(v, graph_id, whi, wlo, E_b, gmA_b,
                                        gmB_lin, s2m_g, gm_bih, gm_bhh,
                                        nbuf, (float*)d_out, ilo);
  }
}

// Round 4
// 1291.276 us; speedup vs baseline: 1.6296x; 1.2773x over previous
//
#include <hip/hip_runtime.h>
#include <math.h>

typedef unsigned int u32;
typedef unsigned short u16;

#define N_NODES 100000
#define N_EDGES 1000000
#define NB      64
#define NODES_PER_G 1562   // N // B; graph 63 holds 1594
#define CH64 25            // ceil(1594/64)

typedef __attribute__((ext_vector_type(8))) short bf16x8;   // 8 bf16 = 4 VGPR
typedef __attribute__((ext_vector_type(4))) float f32x4;
#define MFMA16 __builtin_amdgcn_mfma_f32_16x16x32_bf16

__device__ __forceinline__ float sigmoidf_(float x){ return 1.f/(1.f+__expf(-x)); }
__device__ __forceinline__ float ftanh(float x){
  float e = __expf(-2.f*fabsf(x));
  float t = (1.f - e)/(1.f + e);
  return copysignf(t, x);
}

// streaming 128-dot: weights from global (L2-hot), x from LDS
__device__ __forceinline__ float dots(const float* w, const float* x){
  const float4* w4 = (const float4*)w;
  float a = 0.f;
#pragma unroll 8
  for(int i=0;i<32;i++){
    float4 t = w4[i];
    a = fmaf(t.x, x[4*i+0], a);
    a = fmaf(t.y, x[4*i+1], a);
    a = fmaf(t.z, x[4*i+2], a);
    a = fmaf(t.w, x[4*i+3], a);
  }
  return a;
}

// Dekker split: x = hi + lo, both bf16 (truncation); residual ~2^-16 relative
__device__ __forceinline__ void cvt2(float a, float b, u32 &hi, u32 &lo){
  u32 ab = __float_as_uint(a), bb = __float_as_uint(b);
  hi = (ab>>16) | (bb & 0xffff0000u);
  float ar = a - __uint_as_float(ab & 0xffff0000u);
  float br = b - __uint_as_float(bb & 0xffff0000u);
  lo = (__float_as_uint(ar)>>16) | (__float_as_uint(br) & 0xffff0000u);
}

// ------------- one-time weight split: fp32 -> bf16 hi/lo arrays in ws -------------
// flat u16 index: [E_w 32768][gmA_w 16384][gm_wih 49152][gm_whh 49152][mA_w 65536]
__global__ __launch_bounds__(256) void k_prep(const float* __restrict__ ew,
                    const float* __restrict__ ga,
                    const float* __restrict__ wih,
                    const float* __restrict__ whh,
                    const float* __restrict__ maw,
                    u16* __restrict__ hi, u16* __restrict__ lo){
  int i = blockIdx.x*256 + threadIdx.x;
  float x;
  if(i < 32768) x = ew[i];
  else if(i < 49152) x = ga[i-32768];
  else if(i < 98304) x = wih[i-49152];
  else if(i < 147456) x = whh[i-98304];
  else if(i < 212992) x = maw[i-147456];
  else return;
  u32 b = __float_as_uint(x);
  u16 h = (u16)(b>>16);
  float hf = __uint_as_float((u32)h<<16);
  float l = x - hf;
  hi[i] = h;
  lo[i] = (u16)(__float_as_uint(l)>>16);
}

// ---------------- per-graph precompute: s2s, s2m, w2(=dsup*mC), gmB_lin ----------
__global__ __launch_bounds__(128,4) void k_sup(const float* __restrict__ s,
                      const float* A_w, const float* A_b,
                      const float* C_w, const float* C_b,
                      const float* mB_w, const float* mB_b, const float* mC_w,
                      const float* gmB_w, const float* gmB_b,
                      float* s2s, float* s2m_g, float* w2, float* gmB_lin){
  int b = blockIdx.x, h = threadIdx.x;
  __shared__ float sb[128], s2ml[128];
  sb[h] = s[b*128+h];
  __syncthreads();
  s2s[b*128+h] = ftanh(dots(A_w + h*128, sb) + A_b[h]);
  float sm = ftanh(dots(C_w + h*128, sb) + C_b[h]);
  s2m_g[b*128+h] = sm; s2ml[h] = sm;
  for(int k=0;k<4;k++){
    float d = ftanh(dots(mB_w + (size_t)(k*128+h)*128, sb) + mB_b[k*128+h]);
    w2[b*512 + k*128 + h] = d * mC_w[k*128+h];
  }
  __syncthreads();
  gmB_lin[b*128+h] = dots(gmB_w + h*128, s2ml) + gmB_b[h];
}

// ------------- attention logits + weighted node-sum y, 64 nodes/block -------------
// 256 thr / 4 waves; wave wv = head. Per weight tile tt (16 rows), 4 independent
// node-group MFMA chains (ng) reuse the same weight fragments -> 4x ILP + 4x L2 amortize.
// mD matvec hoisted to k_sup2 via linearity: yg[g] += sum_n exp(logit_n) * v_n.
__global__ __launch_bounds__(256,3) void k_att(const float* __restrict__ v,
                      const float* __restrict__ w2,
                      const u16* __restrict__ mAhi, const u16* __restrict__ mAlo,
                      const float* __restrict__ mA_b, const float* __restrict__ mC_b,
                      float* __restrict__ asum, float* __restrict__ yg){
  int g = blockIdx.x / CH64, chunk = blockIdx.x % CH64;
  int start = g*NODES_PER_G, end = (g==NB-1)? N_NODES : start+NODES_PER_G;
  int node0 = start + chunk*64;
  int cnt = end - node0; if(cnt<=0) return; if(cnt>64) cnt=64;
  int t = threadIdx.x;
  int lane = t & 63, wv = t>>6;      // wv = head
  int lr = lane & 15, lg = lane >> 4;
  int koff = lg*8;

  __shared__ u16 XH[64][136], XL[64][136];   // v split; 272B row stride
  __shared__ float ael[64][4];
  __shared__ float yq[4][4][128];            // per-quarter partial y
  __shared__ float wl2s[512], bAs[512];

  for(int i=t;i<64*32;i+=256){
    int n=i>>5, c=i&31;
    float4 val = (n<cnt) ? ((const float4*)(v + (size_t)(node0+n)*128))[c]
                         : make_float4(0.f,0.f,0.f,0.f);
    int cc = c<<2;
    u32 h01,l01,h23,l23;
    cvt2(val.x,val.y,h01,l01); cvt2(val.z,val.w,h23,l23);
    *(uint2*)&XH[n][cc] = make_uint2(h01,h23);
    *(uint2*)&XL[n][cc] = make_uint2(l01,l23);
  }
  for(int i=t;i<512;i+=256){ wl2s[i]=w2[g*512+i]; bAs[i]=mA_b[i]; }
  __syncthreads();

  // ---- logits: tt = weight tile (16 rows of head wv), ng = node group (16 nodes)
  float sr[4][4];
#pragma unroll
  for(int ng=0;ng<4;ng++){
#pragma unroll
    for(int r=0;r<4;r++) sr[ng][r]=0.f;
  }

  for(int tt=0; tt<8; tt++){
    int row = wv*128 + tt*16 + lr;
    const u16* bh  = mAhi + (size_t)row*128 + koff;
    const u16* bl_ = mAlo + (size_t)row*128 + koff;
    bf16x8 wh[4], wl[4];
#pragma unroll
    for(int ks=0;ks<4;ks++){
      wh[ks] = *(const bf16x8*)(bh  + ks*32);
      wl[ks] = *(const bf16x8*)(bl_ + ks*32);
    }
    float bb = bAs[row], ww = wl2s[row];
#pragma unroll
    for(int ng=0;ng<4;ng++){
      const u16* pah = &XH[ng*16+lr][koff];
      const u16* pal = &XL[ng*16+lr][koff];
      f32x4 acc = {0.f,0.f,0.f,0.f};
#pragma unroll
      for(int ks=0;ks<4;ks++){
        bf16x8 ah = *(const bf16x8*)(pah + ks*32);
        bf16x8 al = *(const bf16x8*)(pal + ks*32);
        acc = MFMA16(ah, wh[ks], acc, 0,0,0);
        acc = MFMA16(ah, wl[ks], acc, 0,0,0);
        acc = MFMA16(al, wh[ks], acc, 0,0,0);
      }
#pragma unroll
      for(int r=0;r<4;r++) sr[ng][r] += ftanh(acc[r]+bb)*ww;
    }
  }
  // reduce over the 16 col-lanes (weight rows within tile)
#pragma unroll
  for(int ng=0;ng<4;ng++){
#pragma unroll
    for(int m=1;m<16;m<<=1){
      sr[ng][0] += __shfl_xor(sr[ng][0], m, 64);
      sr[ng][1] += __shfl_xor(sr[ng][1], m, 64);
      sr[ng][2] += __shfl_xor(sr[ng][2], m, 64);
      sr[ng][3] += __shfl_xor(sr[ng][3], m, 64);
    }
  }
  if(lr==0){
    float cb = mC_b[wv], la = 0.f;
#pragma unroll
    for(int ng=0;ng<4;ng++){
#pragma unroll
      for(int r=0;r<4;r++){
        int n = ng*16 + lg*4 + r;
        float ae = (n<cnt)? __expf(sr[ng][r]+cb) : 0.f;
        ael[n][wv] = ae; la += ae;
      }
    }
    atomicAdd(&asum[g*4+wv], la);
  }
  __syncthreads();

  // ---- y partials: thread (q=node quarter, kk=head, co=col octet)
  {
    int q = t>>6, kk = (t>>4)&3, co = t&15;
    float a8[8];
#pragma unroll
    for(int j=0;j<8;j++) a8[j]=0.f;
    for(int n=q*16; n<q*16+16; n++){
      float w = ael[n][kk];
      bf16x8 hh = *(const bf16x8*)&XH[n][co*8];
      bf16x8 ll = *(const bf16x8*)&XL[n][co*8];
#pragma unroll
      for(int j=0;j<8;j++){
        float vv = __uint_as_float(((u32)(u16)hh[j])<<16)
                 + __uint_as_float(((u32)(u16)ll[j])<<16);
        a8[j] = fmaf(w, vv, a8[j]);
      }
    }
#pragma unroll
    for(int j=0;j<8;j++) yq[q][kk][co*8+j] = a8[j];
  }
  __syncthreads();
  {
    int c = t&127, k0 = t>>7;
#pragma unroll
    for(int jj=0;jj<2;jj++){
      int k = k0 + jj*2;
      float y = yq[0][k][c]+yq[1][k][c]+yq[2][k][c]+yq[3][k][c];
      atomicAdd(&yg[(size_t)g*512 + k*128 + c], y);
    }
  }
}

// ---------------- edge message + scatter-add into nbuf (dst-range filtered) -------
__global__ __launch_bounds__(128,4) void k_edge(const float* __restrict__ v, const float* __restrict__ e,
                       const int* __restrict__ src, const int* __restrict__ dst,
                       const float* K_w, const float* K_b,
                       float* __restrict__ nbuf, int lo, int hi){
  int h = threadIdx.x;
  int e0 = blockIdx.x * 16;
  __shared__ float el[16][16];
  __shared__ int sl[16], dl[16];
  for(int i=h;i<256;i+=128){ int ee=i>>4, c=i&15; el[ee][c]=e[(size_t)(e0+ee)*16+c]; }
  if(h<16){ sl[h]=src[e0+h]; dl[h]=dst[e0+h]; }
  float4 kw[4];
  { const float4* q=(const float4*)(K_w + h*16);
    kw[0]=q[0]; kw[1]=q[1]; kw[2]=q[2]; kw[3]=q[3]; }
  float kb = K_b[h];
  __syncthreads();
  for(int j=0;j<16;j++){
    int dj = dl[j];
    if(dj < lo || dj >= hi) continue;
    int sj = sl[j]; if((u32)sj >= (u32)N_NODES) sj = 0;
    float kv=kb;
#pragma unroll
    for(int i=0;i<4;i++){
      float4 t = kw[i];
      kv = fmaf(t.x, el[j][4*i+0], kv);
      kv = fmaf(t.y, el[j][4*i+1], kv);
      kv = fmaf(t.z, el[j][4*i+2], kv);
      kv = fmaf(t.w, el[j][4*i+3], kv);
    }
    float vs = v[(size_t)sj*128+h];
    float val = kv*vs; val = (val>0.f)? val : 0.1f*val;
    atomicAdd(&nbuf[(size_t)(dj-lo)*128+h], val);
  }
}

// ---------------- fused node pipeline via split-bf16 MFMA -------------------------
__global__ __launch_bounds__(256,2) void k_node(
    const float* __restrict__ v, const int* __restrict__ graph_id,
    const u16* __restrict__ whi, const u16* __restrict__ wlo,
    const float* __restrict__ E_b, const float* __restrict__ gmA_b,
    const float* __restrict__ gmB_lin, const float* __restrict__ s2m_g,
    const float* __restrict__ bih, const float* __restrict__ bhh,
    const float* __restrict__ nbuf, float* __restrict__ out, int lo_){
  int t = threadIdx.x;
  int nl0 = blockIdx.x*16;
  int node0 = lo_ + nl0;
  int lane = t & 63, wv = t>>6;
  int lr = lane & 15, lg = lane >> 4;
  int koff = lg*8;

  __shared__ u16 XH[16][264];
  __shared__ u16 XL[16][264];
  __shared__ float ML[16][128];      // m2m -> hgate (fp32)
  __shared__ float scr[3][16][128];  // gh gates (+bias) from waves 2,3
  __shared__ int gid[16];

  for(int i=t; i<16*64; i+=256){
    int n = i>>6, c4 = i&63;
    float4 val = (c4<32) ? ((const float4*)(nbuf + (size_t)(nl0+n)*128))[c4]
                         : ((const float4*)(v + (size_t)(node0+n)*128))[c4-32];
    int c = c4<<2;
    u32 h01,l01,h23,l23;
    cvt2(val.x, val.y, h01, l01);
    cvt2(val.z, val.w, h23, l23);
    *(uint2*)&XH[n][c] = make_uint2(h01, h23);
    *(uint2*)&XL[n][c] = make_uint2(l01, l23);
  }
  if(t<16) gid[t] = graph_id[node0+t] & 63;
  __syncthreads();

  // ---- phase 1: m2m = leaky(E_w @ [sve; v] + E_b)
  {
    f32x4 acc[2] = {{0.f,0.f,0.f,0.f},{0.f,0.f,0.f,0.f}};
    int hrow = (wv*2)*16 + lr;
    const u16* b0h = whi + (size_t)hrow*256 + koff;
    const u16* b0l = wlo + (size_t)hrow*256 + koff;
    const u16* b1h = b0h + 16*256;
    const u16* b1l = b0l + 16*256;
    const u16* pah = &XH[lr][koff];
    const u16* pal = &XL[lr][koff];
#pragma unroll
    for(int ks=0; ks<8; ks++){
      bf16x8 ah  = *(const bf16x8*)(pah + ks*32);
      bf16x8 al  = *(const bf16x8*)(pal + ks*32);
      bf16x8 w0h = *(const bf16x8*)(b0h + ks*32);
      bf16x8 w0l = *(const bf16x8*)(b0l + ks*32);
      bf16x8 w1h = *(const bf16x8*)(b1h + ks*32);
      bf16x8 w1l = *(const bf16x8*)(b1l + ks*32);
      acc[0] = MFMA16(ah, w0h, acc[0], 0,0,0);
      acc[0] = MFMA16(ah, w0l, acc[0], 0,0,0);
      acc[0] = MFMA16(al, w0h, acc[0], 0,0,0);
      acc[1] = MFMA16(ah, w1h, acc[1], 0,0,0);
      acc[1] = MFMA16(ah, w1l, acc[1], 0,0,0);
      acc[1] = MFMA16(al, w1h, acc[1], 0,0,0);
    }
    __syncthreads();
#pragma unroll
    for(int tt=0; tt<2; tt++){
      int hcol = (wv*2+tt)*16 + lr;
      float eb = E_b[hcol];
#pragma unroll
      for(int r=0; r<4; r++){
        int n = lg*4 + r;
        float m = acc[tt][r] + eb;
        m = (m>0.f)? m : 0.1f*m;
        ML[n][hcol] = m;
        u32 mb = __float_as_uint(m);
        u16 mh = (u16)(mb>>16);
        XH[n][hcol] = mh;
        float mlr = m - __uint_as_float((u32)mh<<16);
        XL[n][hcol] = (u16)(__float_as_uint(mlr)>>16);
      }
    }
    __syncthreads();
  }

  // ---- phase 2: z = sigmoid(gmA@m2m + gmA_b + gmB_lin); hgate = z*s2m + (1-z)*m2m
  {
    const u16* gah = whi + 32768;
    const u16* gal = wlo + 32768;
    f32x4 acc[2] = {{0.f,0.f,0.f,0.f},{0.f,0.f,0.f,0.f}};
    int hrow = (wv*2)*16 + lr;
    const u16* b0h = gah + (size_t)hrow*128 + koff;
    const u16* b0l = gal + (size_t)hrow*128 + koff;
    const u16* b1h = b0h + 16*128;
    const u16* b1l = b0l + 16*128;
    const u16* pah = &XH[lr][koff];
    const u16* pal = &XL[lr][koff];
#pragma unroll
    for(int ks=0; ks<4; ks++){
      bf16x8 ah  = *(const bf16x8*)(pah + ks*32);
      bf16x8 al  = *(const bf16x8*)(pal + ks*32);
      bf16x8 w0h = *(const bf16x8*)(b0h + ks*32);
      bf16x8 w0l = *(const bf16x8*)(b0l + ks*32);
      bf16x8 w1h = *(const bf16x8*)(b1h + ks*32);
      bf16x8 w1l = *(const bf16x8*)(b1l + ks*32);
      acc[0] = MFMA16(ah, w0h, acc[0], 0,0,0);
      acc[0] = MFMA16(ah, w0l, acc[0], 0,0,0);
      acc[0] = MFMA16(al, w0h, acc[0], 0,0,0);
      acc[1] = MFMA16(ah, w1h, acc[1], 0,0,0);
      acc[1] = MFMA16(ah, w1l, acc[1], 0,0,0);
      acc[1] = MFMA16(al, w1h, acc[1], 0,0,0);
    }
    __syncthreads();
#pragma unroll
    for(int tt=0; tt<2; tt++){
      int hcol = (wv*2+tt)*16 + lr;
      float ab = gmA_b[hcol];
#pragma unroll
      for(int r=0; r<4; r++){
        int n = lg*4 + r;
        int g = gid[n];
        float z = sigmoidf_(acc[tt][r] + ab + gmB_lin[g*128+hcol]);
        float hg = z*s2m_g[g*128+hcol] + (1.f-z)*ML[n][hcol];
        ML[n][hcol] = hg;
        u32 mb = __float_as_uint(hg);
        u16 mh = (u16)(mb>>16);
        XH[n][hcol] = mh;
        float mlr = hg - __uint_as_float((u32)mh<<16);
        XL[n][hcol] = (u16)(__float_as_uint(mlr)>>16);
      }
    }
    __syncthreads();
  }

  // ---- phase 3: GRU. waves 0,1: gi = wih@v ; waves 2,3: gh = whh@hgate
  {
    const u16* wbh; const u16* wbl; int xoff;
    if(wv < 2){ wbh = whi + 49152; wbl = wlo + 49152; xoff = 128; }
    else      { wbh = whi + 98304; wbl = wlo + 98304; xoff = 0;   }
    int wp = wv & 1;
    f32x4 acc[3][4];
#pragma unroll
    for(int j=0;j<3;j++)
#pragma unroll
      for(int tt=0;tt<4;tt++){ f32x4 z4 = {0.f,0.f,0.f,0.f}; acc[j][tt]=z4; }
    const u16* pah = &XH[lr][xoff + koff];
    const u16* pal = &XL[lr][xoff + koff];
#pragma unroll
    for(int ks=0; ks<4; ks++){
      bf16x8 ah = *(const bf16x8*)(pah + ks*32);
      bf16x8 al = *(const bf16x8*)(pal + ks*32);
#pragma unroll
      for(int j=0;j<3;j++){
#pragma unroll
        for(int tt=0;tt<4;tt++){
          int row = j*128 + (wp*4+tt)*16 + lr;
          bf16x8 wh_ = *(const bf16x8*)(wbh + (size_t)row*128 + koff + ks*32);
          bf16x8 wl_ = *(const bf16x8*)(wbl + (size_t)row*128 + koff + ks*32);
          acc[j][tt] = MFMA16(ah, wh_, acc[j][tt], 0,0,0);
          acc[j][tt] = MFMA16(ah, wl_, acc[j][tt], 0,0,0);
          acc[j][tt] = MFMA16(al, wh_, acc[j][tt], 0,0,0);
        }
      }
    }
    if(wv >= 2){
#pragma unroll
      for(int j=0;j<3;j++){
#pragma unroll
        for(int tt=0;tt<4;tt++){
          int hh = (wp*4+tt)*16 + lr;
          float bb = bhh[j*128+hh];
#pragma unroll
          for(int r=0;r<4;r++) scr[j][lg*4+r][hh] = acc[j][tt][r] + bb;
        }
      }
    }
    __syncthreads();
    if(wv < 2){
#pragma unroll
      for(int tt=0;tt<4;tt++){
        int hh = (wp*4+tt)*16 + lr;
        float b0 = bih[hh], b1 = bih[128+hh], b2 = bih[256+hh];
#pragma unroll
        for(int r=0;r<4;r++){
          int n = lg*4 + r;
          float gi0 = acc[0][tt][r] + b0;
          float gi1 = acc[1][tt][r] + b1;
          float gi2 = acc[2][tt][r] + b2;
          float rr = sigmoidf_(gi0 + scr[0][n][hh]);
          float zz = sigmoidf_(gi1 + scr[1][n][hh]);
          float nn = ftanh(gi2 + rr*scr[2][n][hh]);
          float hg = ML[n][hh];
          out[(size_t)(node0+n)*128 + hh] = (1.f-zz)*nn + zz*hg;
        }
      }
    }
  }
}

// ---------------- supernode finish: m2s (incl. hoisted mD), gate, GRU -------------
__global__ __launch_bounds__(128,4) void k_sup2(const float* __restrict__ s,
                       const float* __restrict__ yg, const float* __restrict__ asum,
                       const float* __restrict__ s2s,
                       const float* mD_w, const float* mD_b,
                       const float* B_w, const float* B_b,
                       const float* gsA_w, const float* gsA_b,
                       const float* gsB_w, const float* gsB_b,
                       const float* wih, const float* bih, const float* whh, const float* bhh,
                       float* __restrict__ out){
  int b=blockIdx.x, h=threadIdx.x;
  __shared__ float ygl[512], m2si[512], m2sl[128], s2sl[128], sl[128], hgl[128];
  for(int j=0;j<4;j++){ int kh=h+j*128; ygl[kh]=yg[b*512+kh]; }
  s2sl[h]=s2s[b*128+h];
  sl[h]=s[b*128+h];
  __syncthreads();
  // m2s numerator row kh = mD_w[kh] @ yg[k] / asum[k] + mD_b[kh]   (hoisted from k_att)
  for(int j=0;j<4;j++){
    int kh=h+j*128; int k=kh>>7;
    m2si[kh] = dots(mD_w + (size_t)kh*128, &ygl[k*128]) / asum[b*4+k] + mD_b[kh];
  }
  __syncthreads();
  float acc = B_b[h];
  { const float4* q=(const float4*)(B_w + (size_t)h*512);
#pragma unroll 8
    for(int i=0;i<128;i++){
      float4 p=q[i]; int base=i*4;
      acc=fmaf(p.x,m2si[base+0],acc); acc=fmaf(p.y,m2si[base+1],acc);
      acc=fmaf(p.z,m2si[base+2],acc); acc=fmaf(p.w,m2si[base+3],acc);
    }
  }
  float m2sv = ftanh(acc);
  m2sl[h]=m2sv;
  __syncthreads();
  float zacc = dots(gsA_w+(size_t)h*128, s2sl) + gsA_b[h];
  zacc      += dots(gsB_w+(size_t)h*128, m2sl) + gsB_b[h];
  float z = sigmoidf_(zacc);
  float hg = z*m2sl[h] + (1.f-z)*s2sl[h];
  hgl[h]=hg;
  __syncthreads();
  float gi[3], gh[3];
  for(int j=0;j<3;j++){
    gi[j]=dots(wih+(size_t)(h+j*128)*128, sl)+bih[h+j*128];
    gh[j]=dots(whh+(size_t)(h+j*128)*128, hgl)+bhh[h+j*128];
  }
  float r=sigmoidf_(gi[0]+gh[0]), z2=sigmoidf_(gi[1]+gh[1]);
  float nn=ftanh(gi[2]+r*gh[2]);
  out[(size_t)N_NODES*128 + b*128 + h] = (1.f-z2)*nn + z2*hg;
}

extern "C" void kernel_launch(void* const* d_in, const int* in_sizes, int n_in,
                              void* d_out, int out_size, void* d_ws, size_t ws_size,
                              hipStream_t stream){
  const float* v   = (const float*)d_in[0];
  const float* e   = (const float*)d_in[1];
  const float* s   = (const float*)d_in[2];
  const int* src  = (const int*)d_in[3];
  const int* dst  = (const int*)d_in[4];
  const int* graph_id = (const int*)d_in[5];
  const float* A_w=(const float*)d_in[6];  const float* A_b=(const float*)d_in[7];
  const float* B_w=(const float*)d_in[8];  const float* B_b=(const float*)d_in[9];
  const float* C_w=(const float*)d_in[10]; const float* C_b=(const float*)d_in[11];
  const float* E_w=(const float*)d_in[12]; const float* E_b=(const float*)d_in[13];
  const float* K_w=(const float*)d_in[14]; const float* K_b=(const float*)d_in[15];
  const float* mA_w=(const float*)d_in[16]; const float* mA_b=(const float*)d_in[17];
  const float* mB_w=(const float*)d_in[18]; const float* mB_b=(const float*)d_in[19];
  const float* mC_w=(const float*)d_in[20]; const float* mC_b=(const float*)d_in[21];
  const float* mD_w=(const float*)d_in[22]; const float* mD_b=(const float*)d_in[23];
  const float* gmA_w=(const float*)d_in[24]; const float* gmA_b=(const float*)d_in[25];
  const float* gmB_w=(const float*)d_in[26]; const float* gmB_b=(const float*)d_in[27];
  const float* gm_wih=(const float*)d_in[28]; const float* gm_bih=(const float*)d_in[29];
  const float* gm_whh=(const float*)d_in[30]; const float* gm_bhh=(const float*)d_in[31];
  const float* gsA_w=(const float*)d_in[32]; const float* gsA_b=(const float*)d_in[33];
  const float* gsB_w=(const float*)d_in[34]; const float* gsB_b=(const float*)d_in[35];
  const float* gs_wih=(const float*)d_in[36]; const float* gs_bih=(const float*)d_in[37];
  const float* gs_whh=(const float*)d_in[38]; const float* gs_bhh=(const float*)d_in[39];

  float* ws = (float*)d_ws;
  float* asum    = ws;                  // 256
  float* yg      = asum + 256;          // 32768  (per-graph weighted node sums)
  float* s2s     = yg + 32768;          // 8192
  float* s2m_g   = s2s + 8192;          // 8192
  float* gmB_lin = s2m_g + 8192;        // 8192
  float* w2      = gmB_lin + 8192;      // 32768
  u16*   whi     = (u16*)(w2 + 32768);  // 212992 u16 (hi)
  u16*   wlo     = whi + 212992;        // 212992 u16 (lo)
  float* nbuf    = (float*)(wlo + 212992);
  const size_t small_f = 256 + 32768 + 8192*3 + 32768 + 212992;   // 303360 floats

  size_t ws_f = ws_size / 4;
  long avail = (ws_f > small_f) ? (long)(ws_f - small_f) : 0;
  long M = (avail / 128) & ~15L;
  if(M > N_NODES) M = N_NODES;
  if(M < 16) M = 16;

  hipMemsetAsync(asum, 0, (256 + 32768) * sizeof(float), stream);

  k_prep<<<832, 256, 0, stream>>>(E_w, gmA_w, gm_wih, gm_whh, mA_w, whi, wlo);
  k_sup <<<NB, 128, 0, stream>>>(s, A_w,A_b, C_w,C_b, mB_w,mB_b,mC_w, gmB_w,gmB_b,
                                 s2s, s2m_g, w2, gmB_lin);
  k_att <<<NB*CH64, 256, 0, stream>>>(v, w2, whi + 147456, wlo + 147456,
                                      mA_b, mC_b, asum, yg);
  k_sup2<<<NB, 128, 0, stream>>>(s, yg, asum, s2s, mD_w, mD_b, B_w,B_b,
                                 gsA_w,gsA_b, gsB_w,gsB_b,
                                 gs_wih,gs_bih, gs_whh,gs_bhh, (float*)d_out);

  for(long lo = 0; lo < N_NODES; lo += M){
    long cnt = N_NODES - lo; if(cnt > M) cnt = M;
    int ilo = (int)lo, icnt = (int)cnt;
    hipMemsetAsync(nbuf, 0, (size_t)icnt*128*sizeof(float), stream);
    k_edge<<<N_EDGES/16, 128, 0, stream>>>(v, e, src, dst, K_w, K_b, nbuf, ilo, ilo+icnt);
    k_node<<<icnt/16, 256, 0, stream>>>(v, graph_id, whi, wlo, E_b, gmA_b,
                                        gmB_lin, s2m_g, gm_bih, gm_bhh,
                                        nbuf, (float*)d_out, ilo);
  }
}

// Round 5
// 1174.870 us; speedup vs baseline: 1.7911x; 1.0991x over previous
//
#include <hip/hip_runtime.h>
#include <math.h>

typedef unsigned int u32;
typedef unsigned short u16;

#define N_NODES 100000
#define N_EDGES 1000000
#define NB      64
#define NODES_PER_G 1562   // N // B; graph 63 holds 1594
#define CH64 25            // ceil(1594/64)

typedef __attribute__((ext_vector_type(8))) short bf16x8;   // 8 bf16 = 4 VGPR
typedef __attribute__((ext_vector_type(4))) float f32x4;
#define MFMA16 __builtin_amdgcn_mfma_f32_16x16x32_bf16

__device__ __forceinline__ float sigmoidf_(float x){ return 1.f/(1.f+__expf(-x)); }
__device__ __forceinline__ float ftanh(float x){
  float e = __expf(-2.f*fabsf(x));
  float t = (1.f - e)/(1.f + e);
  return copysignf(t, x);
}

__device__ __forceinline__ float dots(const float* w, const float* x){
  const float4* w4 = (const float4*)w;
  float a = 0.f;
#pragma unroll 8
  for(int i=0;i<32;i++){
    float4 t = w4[i];
    a = fmaf(t.x, x[4*i+0], a);
    a = fmaf(t.y, x[4*i+1], a);
    a = fmaf(t.z, x[4*i+2], a);
    a = fmaf(t.w, x[4*i+3], a);
  }
  return a;
}

// Dekker split: x = hi + lo, both bf16 (truncation); residual ~2^-16 relative
__device__ __forceinline__ void cvt2(float a, float b, u32 &hi, u32 &lo){
  u32 ab = __float_as_uint(a), bb = __float_as_uint(b);
  hi = (ab>>16) | (bb & 0xffff0000u);
  float ar = a - __uint_as_float(ab & 0xffff0000u);
  float br = b - __uint_as_float(bb & 0xffff0000u);
  lo = (__float_as_uint(ar)>>16) | (__float_as_uint(br) & 0xffff0000u);
}

// ------------- one-time weight split: fp32 -> bf16 hi/lo arrays in ws -------------
// flat u16 index: [E_w 32768][gmA_w 16384][gm_wih 49152][gm_whh 49152][mA_w 65536]
__global__ __launch_bounds__(256) void k_prep(const float* __restrict__ ew,
                    const float* __restrict__ ga,
                    const float* __restrict__ wih,
                    const float* __restrict__ whh,
                    const float* __restrict__ maw,
                    u16* __restrict__ hi, u16* __restrict__ lo){
  int i = blockIdx.x*256 + threadIdx.x;
  float x;
  if(i < 32768) x = ew[i];
  else if(i < 49152) x = ga[i-32768];
  else if(i < 98304) x = wih[i-49152];
  else if(i < 147456) x = whh[i-98304];
  else if(i < 212992) x = maw[i-147456];
  else return;
  u32 b = __float_as_uint(x);
  u16 h = (u16)(b>>16);
  float hf = __uint_as_float((u32)h<<16);
  float l = x - hf;
  hi[i] = h;
  lo[i] = (u16)(__float_as_uint(l)>>16);
}

// ---------------- per-graph precompute: s2s, s2m, w2(=dsup*mC), gmB_lin ----------
__global__ __launch_bounds__(128,4) void k_sup(const float* __restrict__ s,
                      const float* A_w, const float* A_b,
                      const float* C_w, const float* C_b,
                      const float* mB_w, const float* mB_b, const float* mC_w,
                      const float* gmB_w, const float* gmB_b,
                      float* s2s, float* s2m_g, float* w2, float* gmB_lin){
  int b = blockIdx.x, h = threadIdx.x;
  __shared__ float sb[128], s2ml[128];
  sb[h] = s[b*128+h];
  __syncthreads();
  s2s[b*128+h] = ftanh(dots(A_w + h*128, sb) + A_b[h]);
  float sm = ftanh(dots(C_w + h*128, sb) + C_b[h]);
  s2m_g[b*128+h] = sm; s2ml[h] = sm;
  for(int k=0;k<4;k++){
    float d = ftanh(dots(mB_w + (size_t)(k*128+h)*128, sb) + mB_b[k*128+h]);
    w2[b*512 + k*128 + h] = d * mC_w[k*128+h];
  }
  __syncthreads();
  gmB_lin[b*128+h] = dots(gmB_w + h*128, s2ml) + gmB_b[h];
}

// ------------- attention logits + weighted node-sum y, 64 nodes/block -------------
__global__ __launch_bounds__(256,3) void k_att(const float* __restrict__ v,
                      const float* __restrict__ w2,
                      const u16* __restrict__ mAhi, const u16* __restrict__ mAlo,
                      const float* __restrict__ mA_b, const float* __restrict__ mC_b,
                      float* __restrict__ asum, float* __restrict__ yg){
  int g = blockIdx.x / CH64, chunk = blockIdx.x % CH64;
  int start = g*NODES_PER_G, end = (g==NB-1)? N_NODES : start+NODES_PER_G;
  int node0 = start + chunk*64;
  int cnt = end - node0; if(cnt<=0) return; if(cnt>64) cnt=64;
  int t = threadIdx.x;
  int lane = t & 63, wv = t>>6;      // wv = head
  int lr = lane & 15, lg = lane >> 4;
  int koff = lg*8;

  __shared__ u16 XH[64][136], XL[64][136];
  __shared__ float ael[64][4];
  __shared__ float yq[4][4][128];
  __shared__ float wl2s[512], bAs[512];

  for(int i=t;i<64*32;i+=256){
    int n=i>>5, c=i&31;
    float4 val = (n<cnt) ? ((const float4*)(v + (size_t)(node0+n)*128))[c]
                         : make_float4(0.f,0.f,0.f,0.f);
    int cc = c<<2;
    u32 h01,l01,h23,l23;
    cvt2(val.x,val.y,h01,l01); cvt2(val.z,val.w,h23,l23);
    *(uint2*)&XH[n][cc] = make_uint2(h01,h23);
    *(uint2*)&XL[n][cc] = make_uint2(l01,l23);
  }
  for(int i=t;i<512;i+=256){ wl2s[i]=w2[g*512+i]; bAs[i]=mA_b[i]; }
  __syncthreads();

  float sr[4][4];
#pragma unroll
  for(int ng=0;ng<4;ng++){
#pragma unroll
    for(int r=0;r<4;r++) sr[ng][r]=0.f;
  }

  for(int tt=0; tt<8; tt++){
    int row = wv*128 + tt*16 + lr;
    const u16* bh  = mAhi + (size_t)row*128 + koff;
    const u16* bl_ = mAlo + (size_t)row*128 + koff;
    bf16x8 wh[4], wl[4];
#pragma unroll
    for(int ks=0;ks<4;ks++){
      wh[ks] = *(const bf16x8*)(bh  + ks*32);
      wl[ks] = *(const bf16x8*)(bl_ + ks*32);
    }
    float bb = bAs[row], ww = wl2s[row];
#pragma unroll
    for(int ng=0;ng<4;ng++){
      const u16* pah = &XH[ng*16+lr][koff];
      const u16* pal = &XL[ng*16+lr][koff];
      f32x4 acc = {0.f,0.f,0.f,0.f};
#pragma unroll
      for(int ks=0;ks<4;ks++){
        bf16x8 ah = *(const bf16x8*)(pah + ks*32);
        bf16x8 al = *(const bf16x8*)(pal + ks*32);
        acc = MFMA16(ah, wh[ks], acc, 0,0,0);
        acc = MFMA16(ah, wl[ks], acc, 0,0,0);
        acc = MFMA16(al, wh[ks], acc, 0,0,0);
      }
#pragma unroll
      for(int r=0;r<4;r++) sr[ng][r] += ftanh(acc[r]+bb)*ww;
    }
  }
#pragma unroll
  for(int ng=0;ng<4;ng++){
#pragma unroll
    for(int m=1;m<16;m<<=1){
      sr[ng][0] += __shfl_xor(sr[ng][0], m, 64);
      sr[ng][1] += __shfl_xor(sr[ng][1], m, 64);
      sr[ng][2] += __shfl_xor(sr[ng][2], m, 64);
      sr[ng][3] += __shfl_xor(sr[ng][3], m, 64);
    }
  }
  if(lr==0){
    float cb = mC_b[wv], la = 0.f;
#pragma unroll
    for(int ng=0;ng<4;ng++){
#pragma unroll
      for(int r=0;r<4;r++){
        int n = ng*16 + lg*4 + r;
        float ae = (n<cnt)? __expf(sr[ng][r]+cb) : 0.f;
        ael[n][wv] = ae; la += ae;
      }
    }
    atomicAdd(&asum[g*4+wv], la);
  }
  __syncthreads();

  {
    int q = t>>6, kk = (t>>4)&3, co = t&15;
    float a8[8];
#pragma unroll
    for(int j=0;j<8;j++) a8[j]=0.f;
    for(int n=q*16; n<q*16+16; n++){
      float w = ael[n][kk];
      bf16x8 hh = *(const bf16x8*)&XH[n][co*8];
      bf16x8 ll = *(const bf16x8*)&XL[n][co*8];
#pragma unroll
      for(int j=0;j<8;j++){
        float vv = __uint_as_float(((u32)(u16)hh[j])<<16)
                 + __uint_as_float(((u32)(u16)ll[j])<<16);
        a8[j] = fmaf(w, vv, a8[j]);
      }
    }
#pragma unroll
    for(int j=0;j<8;j++) yq[q][kk][co*8+j] = a8[j];
  }
  __syncthreads();
  {
    int c = t&127, k0 = t>>7;
#pragma unroll
    for(int jj=0;jj<2;jj++){
      int k = k0 + jj*2;
      float y = yq[0][k][c]+yq[1][k][c]+yq[2][k][c]+yq[3][k][c];
      atomicAdd(&yg[(size_t)g*512 + k*128 + c], y);
    }
  }
}

// ---------------- edge message + scatter-add into nbuf (dst-range filtered) -------
__global__ __launch_bounds__(128,4) void k_edge(const float* __restrict__ v, const float* __restrict__ e,
                       const int* __restrict__ src, const int* __restrict__ dst,
                       const float* K_w, const float* K_b,
                       float* __restrict__ nbuf, int lo, int hi){
  int h = threadIdx.x;
  int e0 = blockIdx.x * 16;
  __shared__ float el[16][16];
  __shared__ int sl[16], dl[16];
  for(int i=h;i<256;i+=128){ int ee=i>>4, c=i&15; el[ee][c]=e[(size_t)(e0+ee)*16+c]; }
  if(h<16){ sl[h]=src[e0+h]; dl[h]=dst[e0+h]; }
  float4 kw[4];
  { const float4* q=(const float4*)(K_w + h*16);
    kw[0]=q[0]; kw[1]=q[1]; kw[2]=q[2]; kw[3]=q[3]; }
  float kb = K_b[h];
  __syncthreads();
  for(int j=0;j<16;j++){
    int dj = dl[j];
    if(dj < lo || dj >= hi) continue;
    int sj = sl[j]; if((u32)sj >= (u32)N_NODES) sj = 0;
    float kv=kb;
#pragma unroll
    for(int i=0;i<4;i++){
      float4 t = kw[i];
      kv = fmaf(t.x, el[j][4*i+0], kv);
      kv = fmaf(t.y, el[j][4*i+1], kv);
      kv = fmaf(t.z, el[j][4*i+2], kv);
      kv = fmaf(t.w, el[j][4*i+3], kv);
    }
    float vs = v[(size_t)sj*128+h];
    float val = kv*vs; val = (val>0.f)? val : 0.1f*val;
    atomicAdd(&nbuf[(size_t)(dj-lo)*128+h], val);
  }
}

// ---------------- fused node pipeline, 64 nodes/block, weight-reuse x4 ------------
// 512 thr / 8 waves. Wave wv owns h-tile wv (cols wv*16 + lr) for ALL phases and
// loops node-groups ng=0..3 reusing weight fragments (4 indep MFMA chains).
// m2m and hgate live in registers between phases (D-frag position identical).
__global__ __launch_bounds__(512,4) void k_node(
    const float* __restrict__ v, const int* __restrict__ graph_id,
    const u16* __restrict__ whi, const u16* __restrict__ wlo,
    const float* __restrict__ E_b, const float* __restrict__ gmA_b,
    const float* __restrict__ gmB_lin, const float* __restrict__ s2m_g,
    const float* __restrict__ bih, const float* __restrict__ bhh,
    const float* __restrict__ nbuf, float* __restrict__ out, int lo_, int lim){
  int t = threadIdx.x;
  int nl0 = blockIdx.x*64;
  int node0 = lo_ + nl0;
  int cnt = lim - nl0; if(cnt > 64) cnt = 64;   // valid nodes this block
  int lane = t & 63, wv = t>>6;                 // wv = h-tile 0..7
  int lr = lane & 15, lg = lane >> 4;
  int koff = lg*8;
  int hh = wv*16 + lr;                          // this thread's output column

  __shared__ u16 XH[64][264];    // cols 0..255: [sve|v]; later 0..127 m2m/hgate
  __shared__ u16 XL[64][264];
  __shared__ int gid[64];

  // ---- stage + split-convert X = [sve | v]
  for(int i=t; i<64*64; i+=512){
    int n = i>>6, c4 = i&63;
    float4 val;
    if(n < cnt){
      val = (c4<32) ? ((const float4*)(nbuf + (size_t)(nl0+n)*128))[c4]
                    : ((const float4*)(v + (size_t)(node0+n)*128))[c4-32];
    } else val = make_float4(0.f,0.f,0.f,0.f);
    int c = c4<<2;
    u32 h01,l01,h23,l23;
    cvt2(val.x, val.y, h01, l01);
    cvt2(val.z, val.w, h23, l23);
    *(uint2*)&XH[n][c] = make_uint2(h01, h23);
    *(uint2*)&XL[n][c] = make_uint2(l01, l23);
  }
  if(t<64) gid[t] = (t<cnt) ? (graph_id[node0+t] & 63) : 0;
  __syncthreads();

  // ---- phase 1: m2m = leaky(E_w @ [sve; v] + E_b), K=256
  f32x4 m2m[4];
  {
    f32x4 acc[4];
#pragma unroll
    for(int ng=0;ng<4;ng++){ f32x4 z={0.f,0.f,0.f,0.f}; acc[ng]=z; }
    const u16* bh = whi + (size_t)hh*256 + koff;
    const u16* bl = wlo + (size_t)hh*256 + koff;
#pragma unroll
    for(int ks=0; ks<8; ks++){
      bf16x8 wh_ = *(const bf16x8*)(bh + ks*32);
      bf16x8 wl_ = *(const bf16x8*)(bl + ks*32);
#pragma unroll
      for(int ng=0;ng<4;ng++){
        bf16x8 ah = *(const bf16x8*)&XH[ng*16+lr][koff + ks*32];
        bf16x8 al = *(const bf16x8*)&XL[ng*16+lr][koff + ks*32];
        acc[ng] = MFMA16(ah, wh_, acc[ng], 0,0,0);
        acc[ng] = MFMA16(ah, wl_, acc[ng], 0,0,0);
        acc[ng] = MFMA16(al, wh_, acc[ng], 0,0,0);
      }
    }
    __syncthreads();   // all phase-1 reads done before overwrite
    float eb = E_b[hh];
#pragma unroll
    for(int ng=0;ng<4;ng++){
#pragma unroll
      for(int r=0;r<4;r++){
        float m = acc[ng][r] + eb;
        m = (m>0.f)? m : 0.1f*m;
        m2m[ng][r] = m;
        int n = ng*16 + lg*4 + r;
        u32 mb = __float_as_uint(m);
        u16 mh = (u16)(mb>>16);
        XH[n][hh] = mh;
        float mlr = m - __uint_as_float((u32)mh<<16);
        XL[n][hh] = (u16)(__float_as_uint(mlr)>>16);
      }
    }
    __syncthreads();
  }

  // ---- phase 2: z = sigmoid(gmA@m2m + gmA_b + gmB_lin); hgate = z*s2m + (1-z)*m2m
  f32x4 hgl[4];
  {
    f32x4 acc[4];
#pragma unroll
    for(int ng=0;ng<4;ng++){ f32x4 z={0.f,0.f,0.f,0.f}; acc[ng]=z; }
    const u16* bh = whi + 32768 + (size_t)hh*128 + koff;
    const u16* bl = wlo + 32768 + (size_t)hh*128 + koff;
#pragma unroll
    for(int ks=0; ks<4; ks++){
      bf16x8 wh_ = *(const bf16x8*)(bh + ks*32);
      bf16x8 wl_ = *(const bf16x8*)(bl + ks*32);
#pragma unroll
      for(int ng=0;ng<4;ng++){
        bf16x8 ah = *(const bf16x8*)&XH[ng*16+lr][koff + ks*32];
        bf16x8 al = *(const bf16x8*)&XL[ng*16+lr][koff + ks*32];
        acc[ng] = MFMA16(ah, wh_, acc[ng], 0,0,0);
        acc[ng] = MFMA16(ah, wl_, acc[ng], 0,0,0);
        acc[ng] = MFMA16(al, wh_, acc[ng], 0,0,0);
      }
    }
    __syncthreads();   // phase-2 reads done before hgate overwrite
    float ab = gmA_b[hh];
#pragma unroll
    for(int ng=0;ng<4;ng++){
#pragma unroll
      for(int r=0;r<4;r++){
        int n = ng*16 + lg*4 + r;
        int g = gid[n];
        float z = sigmoidf_(acc[ng][r] + ab + gmB_lin[g*128+hh]);
        float hg = z*s2m_g[g*128+hh] + (1.f-z)*m2m[ng][r];
        hgl[ng][r] = hg;
        u32 mb = __float_as_uint(hg);
        u16 mh = (u16)(mb>>16);
        XH[n][hh] = mh;
        float mlr = hg - __uint_as_float((u32)mh<<16);
        XL[n][hh] = (u16)(__float_as_uint(mlr)>>16);
      }
    }
    __syncthreads();
  }

  // ---- phase 3: GRU gates in order r(j0), n(j2), z(j1); gi=wih@v, gh=whh@hgate
  {
    const u16* wIh = whi + 49152; const u16* wIl = wlo + 49152;
    const u16* wHh = whi + 98304; const u16* wHl = wlo + 98304;
    f32x4 rr[4], nn[4];

#define GRU_GATE(J, BODY) { \
    f32x4 aI[4], aH[4]; \
    _Pragma("unroll") \
    for(int ng=0;ng<4;ng++){ f32x4 z={0.f,0.f,0.f,0.f}; aI[ng]=z; aH[ng]=z; } \
    int row = (J)*128 + hh; \
    const u16* pIh = wIh + (size_t)row*128 + koff; \
    const u16* pIl = wIl + (size_t)row*128 + koff; \
    const u16* pHh = wHh + (size_t)row*128 + koff; \
    const u16* pHl = wHl + (size_t)row*128 + koff; \
    _Pragma("unroll") \
    for(int ks=0; ks<4; ks++){ \
      bf16x8 wi_h = *(const bf16x8*)(pIh + ks*32); \
      bf16x8 wi_l = *(const bf16x8*)(pIl + ks*32); \
      bf16x8 wh_h = *(const bf16x8*)(pHh + ks*32); \
      bf16x8 wh_l = *(const bf16x8*)(pHl + ks*32); \
      _Pragma("unroll") \
      for(int ng=0;ng<4;ng++){ \
        bf16x8 avh = *(const bf16x8*)&XH[ng*16+lr][128 + koff + ks*32]; \
        bf16x8 avl = *(const bf16x8*)&XL[ng*16+lr][128 + koff + ks*32]; \
        bf16x8 agh = *(const bf16x8*)&XH[ng*16+lr][koff + ks*32]; \
        bf16x8 agl = *(const bf16x8*)&XL[ng*16+lr][koff + ks*32]; \
        aI[ng] = MFMA16(avh, wi_h, aI[ng], 0,0,0); \
        aI[ng] = MFMA16(avh, wi_l, aI[ng], 0,0,0); \
        aI[ng] = MFMA16(avl, wi_h, aI[ng], 0,0,0); \
        aH[ng] = MFMA16(agh, wh_h, aH[ng], 0,0,0); \
        aH[ng] = MFMA16(agh, wh_l, aH[ng], 0,0,0); \
        aH[ng] = MFMA16(agl, wh_h, aH[ng], 0,0,0); \
      } \
    } \
    float bI = bih[(J)*128+hh], bH = bhh[(J)*128+hh]; \
    _Pragma("unroll") \
    for(int ng=0;ng<4;ng++){ \
      _Pragma("unroll") \
      for(int r=0;r<4;r++){ \
        float giv = aI[ng][r] + bI; \
        float ghv = aH[ng][r] + bH; \
        BODY \
      } \
    } \
  }

    GRU_GATE(0, { rr[ng][r] = sigmoidf_(giv + ghv); })
    GRU_GATE(2, { nn[ng][r] = ftanh(giv + rr[ng][r]*ghv); })
    GRU_GATE(1, {
      float zz = sigmoidf_(giv + ghv);
      int n = ng*16 + lg*4 + r;
      if(n < cnt)
        out[(size_t)(node0+n)*128 + hh] = (1.f-zz)*nn[ng][r] + zz*hgl[ng][r];
    })
#undef GRU_GATE
  }
}

// ---------------- supernode finish: m2s (incl. hoisted mD), gate, GRU -------------
__global__ __launch_bounds__(128,4) void k_sup2(const float* __restrict__ s,
                       const float* __restrict__ yg, const float* __restrict__ asum,
                       const float* __restrict__ s2s,
                       const float* mD_w, const float* mD_b,
                       const float* B_w, const float* B_b,
                       const float* gsA_w, const float* gsA_b,
                       const float* gsB_w, const float* gsB_b,
                       const float* wih, const float* bih, const float* whh, const float* bhh,
                       float* __restrict__ out){
  int b=blockIdx.x, h=threadIdx.x;
  __shared__ float ygl[512], m2si[512], m2sl[128], s2sl[128], sl[128], hgl[128];
  for(int j=0;j<4;j++){ int kh=h+j*128; ygl[kh]=yg[b*512+kh]; }
  s2sl[h]=s2s[b*128+h];
  sl[h]=s[b*128+h];
  __syncthreads();
  for(int j=0;j<4;j++){
    int kh=h+j*128; int k=kh>>7;
    m2si[kh] = dots(mD_w + (size_t)kh*128, &ygl[k*128]) / asum[b*4+k] + mD_b[kh];
  }
  __syncthreads();
  float acc = B_b[h];
  { const float4* q=(const float4*)(B_w + (size_t)h*512);
#pragma unroll 8
    for(int i=0;i<128;i++){
      float4 p=q[i]; int base=i*4;
      acc=fmaf(p.x,m2si[base+0],acc); acc=fmaf(p.y,m2si[base+1],acc);
      acc=fmaf(p.z,m2si[base+2],acc); acc=fmaf(p.w,m2si[base+3],acc);
    }
  }
  float m2sv = ftanh(acc);
  m2sl[h]=m2sv;
  __syncthreads();
  float zacc = dots(gsA_w+(size_t)h*128, s2sl) + gsA_b[h];
  zacc      += dots(gsB_w+(size_t)h*128, m2sl) + gsB_b[h];
  float z = sigmoidf_(zacc);
  float hg = z*m2sl[h] + (1.f-z)*s2sl[h];
  hgl[h]=hg;
  __syncthreads();
  float gi[3], gh[3];
  for(int j=0;j<3;j++){
    gi[j]=dots(wih+(size_t)(h+j*128)*128, sl)+bih[h+j*128];
    gh[j]=dots(whh+(size_t)(h+j*128)*128, hgl)+bhh[h+j*128];
  }
  float r=sigmoidf_(gi[0]+gh[0]), z2=sigmoidf_(gi[1]+gh[1]);
  float nn=ftanh(gi[2]+r*gh[2]);
  out[(size_t)N_NODES*128 + b*128 + h] = (1.f-z2)*nn + z2*hg;
}

extern "C" void kernel_launch(void* const* d_in, const int* in_sizes, int n_in,
                              void* d_out, int out_size, void* d_ws, size_t ws_size,
                              hipStream_t stream){
  const float* v   = (const float*)d_in[0];
  const float* e   = (const float*)d_in[1];
  const float* s   = (const float*)d_in[2];
  const int* src  = (const int*)d_in[3];
  const int* dst  = (const int*)d_in[4];
  const int* graph_id = (const int*)d_in[5];
  const float* A_w=(const float*)d_in[6];  const float* A_b=(const float*)d_in[7];
  const float* B_w=(const float*)d_in[8];  const float* B_b=(const float*)d_in[9];
  const float* C_w=(const float*)d_in[10]; const float* C_b=(const float*)d_in[11];
  const float* E_w=(const float*)d_in[12]; const float* E_b=(const float*)d_in[13];
  const float* K_w=(const float*)d_in[14]; const float* K_b=(const float*)d_in[15];
  const float* mA_w=(const float*)d_in[16]; const float* mA_b=(const float*)d_in[17];
  const float* mB_w=(const float*)d_in[18]; const float* mB_b=(const float*)d_in[19];
  const float* mC_w=(const float*)d_in[20]; const float* mC_b=(const float*)d_in[21];
  const float* mD_w=(const float*)d_in[22]; const float* mD_b=(const float*)d_in[23];
  const float* gmA_w=(const float*)d_in[24]; const float* gmA_b=(const float*)d_in[25];
  const float* gmB_w=(const float*)d_in[26]; const float* gmB_b=(const float*)d_in[27];
  const float* gm_wih=(const float*)d_in[28]; const float* gm_bih=(const float*)d_in[29];
  const float* gm_whh=(const float*)d_in[30]; const float* gm_bhh=(const float*)d_in[31];
  const float* gsA_w=(const float*)d_in[32]; const float* gsA_b=(const float*)d_in[33];
  const float* gsB_w=(const float*)d_in[34]; const float* gsB_b=(const float*)d_in[35];
  const float* gs_wih=(const float*)d_in[36]; const float* gs_bih=(const float*)d_in[37];
  const float* gs_whh=(const float*)d_in[38]; const float* gs_bhh=(const float*)d_in[39];

  float* ws = (float*)d_ws;
  float* asum    = ws;                  // 256
  float* yg      = asum + 256;          // 32768
  float* s2s     = yg + 32768;          // 8192
  float* s2m_g   = s2s + 8192;          // 8192
  float* gmB_lin = s2m_g + 8192;        // 8192
  float* w2      = gmB_lin + 8192;      // 32768
  u16*   whi     = (u16*)(w2 + 32768);  // 212992 u16 (hi)
  u16*   wlo     = whi + 212992;        // 212992 u16 (lo)
  float* nbuf    = (float*)(wlo + 212992);
  const size_t small_f = 256 + 32768 + 8192*3 + 32768 + 212992;   // 303360 floats

  size_t ws_f = ws_size / 4;
  long avail = (ws_f > small_f) ? (long)(ws_f - small_f) : 0;
  long M = (avail / 128) & ~63L;        // node chunk: multiple of 64
  if(M > N_NODES) M = N_NODES;
  if(M < 64) M = 64;

  hipMemsetAsync(asum, 0, (256 + 32768) * sizeof(float), stream);

  k_prep<<<832, 256, 0, stream>>>(E_w, gmA_w, gm_wih, gm_whh, mA_w, whi, wlo);
  k_sup <<<NB, 128, 0, stream>>>(s, A_w,A_b, C_w,C_b, mB_w,mB_b,mC_w, gmB_w,gmB_b,
                                 s2s, s2m_g, w2, gmB_lin);
  k_att <<<NB*CH64, 256, 0, stream>>>(v, w2, whi + 147456, wlo + 147456,
                                      mA_b, mC_b, asum, yg);
  k_sup2<<<NB, 128, 0, stream>>>(s, yg, asum, s2s, mD_w, mD_b, B_w,B_b,
                                 gsA_w,gsA_b, gsB_w,gsB_b,
                                 gs_wih,gs_bih, gs_whh,gs_bhh, (float*)d_out);

  for(long lo = 0; lo < N_NODES; lo += M){
    long cnt = N_NODES - lo; if(cnt > M) cnt = M;
    int ilo = (int)lo, icnt = (int)cnt;
    hipMemsetAsync(nbuf, 0, (size_t)icnt*128*sizeof(float), stream);
    k_edge<<<N_EDGES/16, 128, 0, stream>>>(v, e, src, dst, K_w, K_b, nbuf, ilo, ilo+icnt);
    k_node<<<(icnt+63)/64, 512, 0, stream>>>(v, graph_id, whi, wlo, E_b, gmA_b,
                                             gmB_lin, s2m_g, gm_bih, gm_bhh,
                                             nbuf, (float*)d_out, ilo, icnt);
  }
}

// Round 6
// 1168.535 us; speedup vs baseline: 1.8008x; 1.0054x over previous
//
#include <hip/hip_runtime.h>
#include <math.h>

typedef unsigned int u32;
typedef unsigned short u16;

#define N_NODES 100000
#define N_EDGES 1000000
#define NB      64
#define NODES_PER_G 1562   // N // B; graph 63 holds 1594
#define CH64 25            // ceil(1594/64)

typedef __attribute__((ext_vector_type(8))) short bf16x8;   // 8 bf16 = 4 VGPR
typedef __attribute__((ext_vector_type(4))) float f32x4;
#define MFMA16 __builtin_amdgcn_mfma_f32_16x16x32_bf16

__device__ __forceinline__ float sigmoidf_(float x){ return 1.f/(1.f+__expf(-x)); }
__device__ __forceinline__ float ftanh(float x){
  float e = __expf(-2.f*fabsf(x));
  float t = (1.f - e)/(1.f + e);
  return copysignf(t, x);
}

__device__ __forceinline__ float dots(const float* w, const float* x){
  const float4* w4 = (const float4*)w;
  float a = 0.f;
#pragma unroll 8
  for(int i=0;i<32;i++){
    float4 t = w4[i];
    a = fmaf(t.x, x[4*i+0], a);
    a = fmaf(t.y, x[4*i+1], a);
    a = fmaf(t.z, x[4*i+2], a);
    a = fmaf(t.w, x[4*i+3], a);
  }
  return a;
}

// Dekker split: x = hi + lo, both bf16 (truncation); residual ~2^-16 relative
__device__ __forceinline__ void cvt2(float a, float b, u32 &hi, u32 &lo){
  u32 ab = __float_as_uint(a), bb = __float_as_uint(b);
  hi = (ab>>16) | (bb & 0xffff0000u);
  float ar = a - __uint_as_float(ab & 0xffff0000u);
  float br = b - __uint_as_float(bb & 0xffff0000u);
  lo = (__float_as_uint(ar)>>16) | (__float_as_uint(br) & 0xffff0000u);
}

// ------------- one-time weight split: fp32 -> bf16 hi/lo arrays in ws -------------
// flat u16 index: [E_w 32768][gmA_w 16384][gm_wih 49152][gm_whh 49152][mA_w 65536]
__global__ __launch_bounds__(256) void k_prep(const float* __restrict__ ew,
                    const float* __restrict__ ga,
                    const float* __restrict__ wih,
                    const float* __restrict__ whh,
                    const float* __restrict__ maw,
                    u16* __restrict__ hi, u16* __restrict__ lo){
  int i = blockIdx.x*256 + threadIdx.x;
  float x;
  if(i < 32768) x = ew[i];
  else if(i < 49152) x = ga[i-32768];
  else if(i < 98304) x = wih[i-49152];
  else if(i < 147456) x = whh[i-98304];
  else if(i < 212992) x = maw[i-147456];
  else return;
  u32 b = __float_as_uint(x);
  u16 h = (u16)(b>>16);
  float hf = __uint_as_float((u32)h<<16);
  float l = x - hf;
  hi[i] = h;
  lo[i] = (u16)(__float_as_uint(l)>>16);
}

// ---------------- per-graph precompute: s2s, s2m, w2(=dsup*mC), gmB_lin ----------
__global__ __launch_bounds__(128,4) void k_sup(const float* __restrict__ s,
                      const float* A_w, const float* A_b,
                      const float* C_w, const float* C_b,
                      const float* mB_w, const float* mB_b, const float* mC_w,
                      const float* gmB_w, const float* gmB_b,
                      float* s2s, float* s2m_g, float* w2, float* gmB_lin){
  int b = blockIdx.x, h = threadIdx.x;
  __shared__ float sb[128], s2ml[128];
  sb[h] = s[b*128+h];
  __syncthreads();
  s2s[b*128+h] = ftanh(dots(A_w + h*128, sb) + A_b[h]);
  float sm = ftanh(dots(C_w + h*128, sb) + C_b[h]);
  s2m_g[b*128+h] = sm; s2ml[h] = sm;
  for(int k=0;k<4;k++){
    float d = ftanh(dots(mB_w + (size_t)(k*128+h)*128, sb) + mB_b[k*128+h]);
    w2[b*512 + k*128 + h] = d * mC_w[k*128+h];
  }
  __syncthreads();
  gmB_lin[b*128+h] = dots(gmB_w + h*128, s2ml) + gmB_b[h];
}

// ------------- attention logits + weighted node-sum y, 64 nodes/block -------------
__global__ __launch_bounds__(256,3) void k_att(const float* __restrict__ v,
                      const float* __restrict__ w2,
                      const u16* __restrict__ mAhi, const u16* __restrict__ mAlo,
                      const float* __restrict__ mA_b, const float* __restrict__ mC_b,
                      float* __restrict__ asum, float* __restrict__ yg){
  int g = blockIdx.x / CH64, chunk = blockIdx.x % CH64;
  int start = g*NODES_PER_G, end = (g==NB-1)? N_NODES : start+NODES_PER_G;
  int node0 = start + chunk*64;
  int cnt = end - node0; if(cnt<=0) return; if(cnt>64) cnt=64;
  int t = threadIdx.x;
  int lane = t & 63, wv = t>>6;      // wv = head
  int lr = lane & 15, lg = lane >> 4;
  int koff = lg*8;

  __shared__ u16 XH[64][136], XL[64][136];
  __shared__ float ael[64][4];
  __shared__ float yq[4][4][128];
  __shared__ float wl2s[512], bAs[512];

  for(int i=t;i<64*32;i+=256){
    int n=i>>5, c=i&31;
    float4 val = (n<cnt) ? ((const float4*)(v + (size_t)(node0+n)*128))[c]
                         : make_float4(0.f,0.f,0.f,0.f);
    int cc = c<<2;
    u32 h01,l01,h23,l23;
    cvt2(val.x,val.y,h01,l01); cvt2(val.z,val.w,h23,l23);
    *(uint2*)&XH[n][cc] = make_uint2(h01,h23);
    *(uint2*)&XL[n][cc] = make_uint2(l01,l23);
  }
  for(int i=t;i<512;i+=256){ wl2s[i]=w2[g*512+i]; bAs[i]=mA_b[i]; }
  __syncthreads();

  float sr[4][4];
#pragma unroll
  for(int ng=0;ng<4;ng++){
#pragma unroll
    for(int r=0;r<4;r++) sr[ng][r]=0.f;
  }

  for(int tt=0; tt<8; tt++){
    int row = wv*128 + tt*16 + lr;
    const u16* bh  = mAhi + (size_t)row*128 + koff;
    const u16* bl_ = mAlo + (size_t)row*128 + koff;
    bf16x8 wh[4], wl[4];
#pragma unroll
    for(int ks=0;ks<4;ks++){
      wh[ks] = *(const bf16x8*)(bh  + ks*32);
      wl[ks] = *(const bf16x8*)(bl_ + ks*32);
    }
    float bb = bAs[row], ww = wl2s[row];
#pragma unroll
    for(int ng=0;ng<4;ng++){
      const u16* pah = &XH[ng*16+lr][koff];
      const u16* pal = &XL[ng*16+lr][koff];
      f32x4 acc = {0.f,0.f,0.f,0.f};
#pragma unroll
      for(int ks=0;ks<4;ks++){
        bf16x8 ah = *(const bf16x8*)(pah + ks*32);
        bf16x8 al = *(const bf16x8*)(pal + ks*32);
        acc = MFMA16(ah, wh[ks], acc, 0,0,0);
        acc = MFMA16(ah, wl[ks], acc, 0,0,0);
        acc = MFMA16(al, wh[ks], acc, 0,0,0);
      }
#pragma unroll
      for(int r=0;r<4;r++) sr[ng][r] += ftanh(acc[r]+bb)*ww;
    }
  }
#pragma unroll
  for(int ng=0;ng<4;ng++){
#pragma unroll
    for(int m=1;m<16;m<<=1){
      sr[ng][0] += __shfl_xor(sr[ng][0], m, 64);
      sr[ng][1] += __shfl_xor(sr[ng][1], m, 64);
      sr[ng][2] += __shfl_xor(sr[ng][2], m, 64);
      sr[ng][3] += __shfl_xor(sr[ng][3], m, 64);
    }
  }
  if(lr==0){
    float cb = mC_b[wv], la = 0.f;
#pragma unroll
    for(int ng=0;ng<4;ng++){
#pragma unroll
      for(int r=0;r<4;r++){
        int n = ng*16 + lg*4 + r;
        float ae = (n<cnt)? __expf(sr[ng][r]+cb) : 0.f;
        ael[n][wv] = ae; la += ae;
      }
    }
    atomicAdd(&asum[g*4+wv], la);
  }
  __syncthreads();

  {
    int q = t>>6, kk = (t>>4)&3, co = t&15;
    float a8[8];
#pragma unroll
    for(int j=0;j<8;j++) a8[j]=0.f;
    for(int n=q*16; n<q*16+16; n++){
      float w = ael[n][kk];
      bf16x8 hh = *(const bf16x8*)&XH[n][co*8];
      bf16x8 ll = *(const bf16x8*)&XL[n][co*8];
#pragma unroll
      for(int j=0;j<8;j++){
        float vv = __uint_as_float(((u32)(u16)hh[j])<<16)
                 + __uint_as_float(((u32)(u16)ll[j])<<16);
        a8[j] = fmaf(w, vv, a8[j]);
      }
    }
#pragma unroll
    for(int j=0;j<8;j++) yq[q][kk][co*8+j] = a8[j];
  }
  __syncthreads();
  {
    int c = t&127, k0 = t>>7;
#pragma unroll
    for(int jj=0;jj<2;jj++){
      int k = k0 + jj*2;
      float y = yq[0][k][c]+yq[1][k][c]+yq[2][k][c]+yq[3][k][c];
      atomicAdd(&yg[(size_t)g*512 + k*128 + c], y);
    }
  }
}

// ---------------- CSR build: histogram, scan, fill --------------------------------
__global__ __launch_bounds__(256) void k_hist(const int* __restrict__ dst, u32* __restrict__ cnt){
  for(int i = blockIdx.x*256 + threadIdx.x; i < N_EDGES; i += 256*1024){
    int d = dst[i];
    if((u32)d < (u32)N_NODES) atomicAdd(&cnt[d], 1u);
  }
}

__global__ __launch_bounds__(1024,1) void k_scan(const u32* __restrict__ cnt,
                         u32* __restrict__ offs, u32* __restrict__ cursor){
  __shared__ u32 wsum[16];
  __shared__ u32 sbase;
  int t = threadIdx.x, lane = t&63, w = t>>6;
  if(t==0) sbase = 0;
  __syncthreads();
  for(int c0=0; c0<N_NODES; c0+=1024){
    int i = c0 + t;
    u32 x = (i<N_NODES)? cnt[i] : 0u;
    u32 vsc = x;
#pragma unroll
    for(int o=1;o<64;o<<=1){ u32 y=__shfl_up(vsc,o,64); if(lane>=o) vsc+=y; }
    if(lane==63) wsum[w]=vsc;
    __syncthreads();
    if(w==0 && lane<16){
      u32 s = wsum[lane];
#pragma unroll
      for(int o=1;o<16;o<<=1){ u32 y=__shfl_up(s,o,64); if(lane>=o) s+=y; }
      wsum[lane]=s;
    }
    __syncthreads();
    u32 base = sbase + (w>0 ? wsum[w-1] : 0u);
    u32 excl = base + vsc - x;
    if(i<N_NODES){ offs[i]=excl; cursor[i]=excl; }
    u32 tot = wsum[15];
    __syncthreads();
    if(t==0) sbase += tot;
    __syncthreads();
  }
  if(t==0) offs[N_NODES] = sbase;
}

__global__ __launch_bounds__(256) void k_fill(const int* __restrict__ src, const int* __restrict__ dst,
                      u32* __restrict__ cursor, uint2* __restrict__ slots){
  for(int i = blockIdx.x*256 + threadIdx.x; i < N_EDGES; i += 256*1024){
    int d = dst[i];
    if((u32)d >= (u32)N_NODES) continue;
    int sj = src[i]; if((u32)sj >= (u32)N_NODES) sj = 0;
    u32 pos = atomicAdd(&cursor[d], 1u);
    slots[pos] = make_uint2((u32)sj, (u32)i);
  }
}

// ---------------- gather edge aggregation: one block per dst node ------------------
__global__ __launch_bounds__(128,8) void k_gath(const float* __restrict__ v,
                       const float* __restrict__ e,
                       const u32* __restrict__ offs, const uint2* __restrict__ slots,
                       const float* __restrict__ K_w, const float* __restrict__ K_b,
                       float* __restrict__ nbuf){
  int d = blockIdx.x;
  int h = threadIdx.x;
  u32 lo = offs[d], hi = offs[d+1];
  float4 kw0,kw1,kw2,kw3;
  { const float4* q=(const float4*)(K_w + h*16); kw0=q[0]; kw1=q[1]; kw2=q[2]; kw3=q[3]; }
  float kb = K_b[h];
  float acc = 0.f;
  __shared__ float el[16][16];
  __shared__ u32 ssrc[16];
  __shared__ u32 seid[16];
  for(u32 base=lo; base<hi; base+=16){
    int chunk = (int)(hi-base); if(chunk>16) chunk=16;
    if(h<chunk){ uint2 sd = slots[base+h]; ssrc[h]=sd.x; seid[h]=sd.y; }
    __syncthreads();
    for(int i=h; i<chunk*16; i+=128){ int j=i>>4, c=i&15; el[j][c] = e[(size_t)seid[j]*16 + c]; }
    __syncthreads();
    for(int j=0;j<chunk;j++){
      float kv = kb;
      kv=fmaf(kw0.x,el[j][0],kv);  kv=fmaf(kw0.y,el[j][1],kv);
      kv=fmaf(kw0.z,el[j][2],kv);  kv=fmaf(kw0.w,el[j][3],kv);
      kv=fmaf(kw1.x,el[j][4],kv);  kv=fmaf(kw1.y,el[j][5],kv);
      kv=fmaf(kw1.z,el[j][6],kv);  kv=fmaf(kw1.w,el[j][7],kv);
      kv=fmaf(kw2.x,el[j][8],kv);  kv=fmaf(kw2.y,el[j][9],kv);
      kv=fmaf(kw2.z,el[j][10],kv); kv=fmaf(kw2.w,el[j][11],kv);
      kv=fmaf(kw3.x,el[j][12],kv); kv=fmaf(kw3.y,el[j][13],kv);
      kv=fmaf(kw3.z,el[j][14],kv); kv=fmaf(kw3.w,el[j][15],kv);
      float vs = v[(size_t)ssrc[j]*128 + h];
      float val = kv*vs; val = (val>0.f)? val : 0.1f*val;
      acc += val;
    }
    __syncthreads();
  }
  nbuf[(size_t)d*128 + h] = acc;
}

// ---------------- fallback edge scatter (atomic), dst-range filtered ---------------
__global__ __launch_bounds__(128,4) void k_edge(const float* __restrict__ v, const float* __restrict__ e,
                       const int* __restrict__ src, const int* __restrict__ dst,
                       const float* K_w, const float* K_b,
                       float* __restrict__ nbuf, int lo, int hi){
  int h = threadIdx.x;
  int e0 = blockIdx.x * 16;
  __shared__ float el[16][16];
  __shared__ int sl[16], dl[16];
  for(int i=h;i<256;i+=128){ int ee=i>>4, c=i&15; el[ee][c]=e[(size_t)(e0+ee)*16+c]; }
  if(h<16){ sl[h]=src[e0+h]; dl[h]=dst[e0+h]; }
  float4 kw[4];
  { const float4* q=(const float4*)(K_w + h*16);
    kw[0]=q[0]; kw[1]=q[1]; kw[2]=q[2]; kw[3]=q[3]; }
  float kb = K_b[h];
  __syncthreads();
  for(int j=0;j<16;j++){
    int dj = dl[j];
    if(dj < lo || dj >= hi) continue;
    int sj = sl[j]; if((u32)sj >= (u32)N_NODES) sj = 0;
    float kv=kb;
#pragma unroll
    for(int i=0;i<4;i++){
      float4 t = kw[i];
      kv = fmaf(t.x, el[j][4*i+0], kv);
      kv = fmaf(t.y, el[j][4*i+1], kv);
      kv = fmaf(t.z, el[j][4*i+2], kv);
      kv = fmaf(t.w, el[j][4*i+3], kv);
    }
    float vs = v[(size_t)sj*128+h];
    float val = kv*vs; val = (val>0.f)? val : 0.1f*val;
    atomicAdd(&nbuf[(size_t)(dj-lo)*128+h], val);
  }
}

// ---------------- fused node pipeline, 64 nodes/block, weight-reuse x4 ------------
__global__ __launch_bounds__(512,4) void k_node(
    const float* __restrict__ v, const int* __restrict__ graph_id,
    const u16* __restrict__ whi, const u16* __restrict__ wlo,
    const float* __restrict__ E_b, const float* __restrict__ gmA_b,
    const float* __restrict__ gmB_lin, const float* __restrict__ s2m_g,
    const float* __restrict__ bih, const float* __restrict__ bhh,
    const float* __restrict__ nbuf, float* __restrict__ out, int lo_, int lim){
  int t = threadIdx.x;
  int nl0 = blockIdx.x*64;
  int node0 = lo_ + nl0;
  int cnt = lim - nl0; if(cnt > 64) cnt = 64;
  int lane = t & 63, wv = t>>6;
  int lr = lane & 15, lg = lane >> 4;
  int koff = lg*8;
  int hh = wv*16 + lr;

  __shared__ u16 XH[64][264];
  __shared__ u16 XL[64][264];
  __shared__ int gid[64];

  for(int i=t; i<64*64; i+=512){
    int n = i>>6, c4 = i&63;
    float4 val;
    if(n < cnt){
      val = (c4<32) ? ((const float4*)(nbuf + (size_t)(nl0+n)*128))[c4]
                    : ((const float4*)(v + (size_t)(node0+n)*128))[c4-32];
    } else val = make_float4(0.f,0.f,0.f,0.f);
    int c = c4<<2;
    u32 h01,l01,h23,l23;
    cvt2(val.x, val.y, h01, l01);
    cvt2(val.z, val.w, h23, l23);
    *(uint2*)&XH[n][c] = make_uint2(h01, h23);
    *(uint2*)&XL[n][c] = make_uint2(l01, l23);
  }
  if(t<64) gid[t] = (t<cnt) ? (graph_id[node0+t] & 63) : 0;
  __syncthreads();

  // ---- phase 1: m2m = leaky(E_w @ [sve; v] + E_b), K=256
  f32x4 m2m[4];
  {
    f32x4 acc[4];
#pragma unroll
    for(int ng=0;ng<4;ng++){ f32x4 z={0.f,0.f,0.f,0.f}; acc[ng]=z; }
    const u16* bh = whi + (size_t)hh*256 + koff;
    const u16* bl = wlo + (size_t)hh*256 + koff;
#pragma unroll
    for(int ks=0; ks<8; ks++){
      bf16x8 wh_ = *(const bf16x8*)(bh + ks*32);
      bf16x8 wl_ = *(const bf16x8*)(bl + ks*32);
#pragma unroll
      for(int ng=0;ng<4;ng++){
        bf16x8 ah = *(const bf16x8*)&XH[ng*16+lr][koff + ks*32];
        bf16x8 al = *(const bf16x8*)&XL[ng*16+lr][koff + ks*32];
        acc[ng] = MFMA16(ah, wh_, acc[ng], 0,0,0);
        acc[ng] = MFMA16(ah, wl_, acc[ng], 0,0,0);
        acc[ng] = MFMA16(al, wh_, acc[ng], 0,0,0);
      }
    }
    __syncthreads();
    float eb = E_b[hh];
#pragma unroll
    for(int ng=0;ng<4;ng++){
#pragma unroll
      for(int r=0;r<4;r++){
        float m = acc[ng][r] + eb;
        m = (m>0.f)? m : 0.1f*m;
        m2m[ng][r] = m;
        int n = ng*16 + lg*4 + r;
        u32 mb = __float_as_uint(m);
        u16 mh = (u16)(mb>>16);
        XH[n][hh] = mh;
        float mlr = m - __uint_as_float((u32)mh<<16);
        XL[n][hh] = (u16)(__float_as_uint(mlr)>>16);
      }
    }
    __syncthreads();
  }

  // ---- phase 2: z = sigmoid(gmA@m2m + gmA_b + gmB_lin); hgate = z*s2m + (1-z)*m2m
  f32x4 hgl[4];
  {
    f32x4 acc[4];
#pragma unroll
    for(int ng=0;ng<4;ng++){ f32x4 z={0.f,0.f,0.f,0.f}; acc[ng]=z; }
    const u16* bh = whi + 32768 + (size_t)hh*128 + koff;
    const u16* bl = wlo + 32768 + (size_t)hh*128 + koff;
#pragma unroll
    for(int ks=0; ks<4; ks++){
      bf16x8 wh_ = *(const bf16x8*)(bh + ks*32);
      bf16x8 wl_ = *(const bf16x8*)(bl + ks*32);
#pragma unroll
      for(int ng=0;ng<4;ng++){
        bf16x8 ah = *(const bf16x8*)&XH[ng*16+lr][koff + ks*32];
        bf16x8 al = *(const bf16x8*)&XL[ng*16+lr][koff + ks*32];
        acc[ng] = MFMA16(ah, wh_, acc[ng], 0,0,0);
        acc[ng] = MFMA16(ah, wl_, acc[ng], 0,0,0);
        acc[ng] = MFMA16(al, wh_, acc[ng], 0,0,0);
      }
    }
    __syncthreads();
    float ab = gmA_b[hh];
#pragma unroll
    for(int ng=0;ng<4;ng++){
#pragma unroll
      for(int r=0;r<4;r++){
        int n = ng*16 + lg*4 + r;
        int g = gid[n];
        float z = sigmoidf_(acc[ng][r] + ab + gmB_lin[g*128+hh]);
        float hg = z*s2m_g[g*128+hh] + (1.f-z)*m2m[ng][r];
        hgl[ng][r] = hg;
        u32 mb = __float_as_uint(hg);
        u16 mh = (u16)(mb>>16);
        XH[n][hh] = mh;
        float mlr = hg - __uint_as_float((u32)mh<<16);
        XL[n][hh] = (u16)(__float_as_uint(mlr)>>16);
      }
    }
    __syncthreads();
  }

  // ---- phase 3: GRU gates in order r(j0), n(j2), z(j1); gi=wih@v, gh=whh@hgate
  {
    const u16* wIh = whi + 49152; const u16* wIl = wlo + 49152;
    const u16* wHh = whi + 98304; const u16* wHl = wlo + 98304;
    f32x4 rr[4], nn[4];

#define GRU_GATE(J, BODY) { \
    f32x4 aI[4], aH[4]; \
    _Pragma("unroll") \
    for(int ng=0;ng<4;ng++){ f32x4 z={0.f,0.f,0.f,0.f}; aI[ng]=z; aH[ng]=z; } \
    int row = (J)*128 + hh; \
    const u16* pIh = wIh + (size_t)row*128 + koff; \
    const u16* pIl = wIl + (size_t)row*128 + koff; \
    const u16* pHh = wHh + (size_t)row*128 + koff; \
    const u16* pHl = wHl + (size_t)row*128 + koff; \
    _Pragma("unroll") \
    for(int ks=0; ks<4; ks++){ \
      bf16x8 wi_h = *(const bf16x8*)(pIh + ks*32); \
      bf16x8 wi_l = *(const bf16x8*)(pIl + ks*32); \
      bf16x8 wh_h = *(const bf16x8*)(pHh + ks*32); \
      bf16x8 wh_l = *(const bf16x8*)(pHl + ks*32); \
      _Pragma("unroll") \
      for(int ng=0;ng<4;ng++){ \
        bf16x8 avh = *(const bf16x8*)&XH[ng*16+lr][128 + koff + ks*32]; \
        bf16x8 avl = *(const bf16x8*)&XL[ng*16+lr][128 + koff + ks*32]; \
        bf16x8 agh = *(const bf16x8*)&XH[ng*16+lr][koff + ks*32]; \
        bf16x8 agl = *(const bf16x8*)&XL[ng*16+lr][koff + ks*32]; \
        aI[ng] = MFMA16(avh, wi_h, aI[ng], 0,0,0); \
        aI[ng] = MFMA16(avh, wi_l, aI[ng], 0,0,0); \
        aI[ng] = MFMA16(avl, wi_h, aI[ng], 0,0,0); \
        aH[ng] = MFMA16(agh, wh_h, aH[ng], 0,0,0); \
        aH[ng] = MFMA16(agh, wh_l, aH[ng], 0,0,0); \
        aH[ng] = MFMA16(agl, wh_h, aH[ng], 0,0,0); \
      } \
    } \
    float bI = bih[(J)*128+hh], bH = bhh[(J)*128+hh]; \
    _Pragma("unroll") \
    for(int ng=0;ng<4;ng++){ \
      _Pragma("unroll") \
      for(int r=0;r<4;r++){ \
        float giv = aI[ng][r] + bI; \
        float ghv = aH[ng][r] + bH; \
        BODY \
      } \
    } \
  }

    GRU_GATE(0, { rr[ng][r] = sigmoidf_(giv + ghv); })
    GRU_GATE(2, { nn[ng][r] = ftanh(giv + rr[ng][r]*ghv); })
    GRU_GATE(1, {
      float zz = sigmoidf_(giv + ghv);
      int n = ng*16 + lg*4 + r;
      if(n < cnt)
        out[(size_t)(node0+n)*128 + hh] = (1.f-zz)*nn[ng][r] + zz*hgl[ng][r];
    })
#undef GRU_GATE
  }
}

// ---------------- supernode finish: m2s (incl. hoisted mD), gate, GRU -------------
__global__ __launch_bounds__(128,4) void k_sup2(const float* __restrict__ s,
                       const float* __restrict__ yg, const float* __restrict__ asum,
                       const float* __restrict__ s2s,
                       const float* mD_w, const float* mD_b,
                       const float* B_w, const float* B_b,
                       const float* gsA_w, const float* gsA_b,
                       const float* gsB_w, const float* gsB_b,
                       const float* wih, const float* bih, const float* whh, const float* bhh,
                       float* __restrict__ out){
  int b=blockIdx.x, h=threadIdx.x;
  __shared__ float ygl[512], m2si[512], m2sl[128], s2sl[128], sl[128], hgl[128];
  for(int j=0;j<4;j++){ int kh=h+j*128; ygl[kh]=yg[b*512+kh]; }
  s2sl[h]=s2s[b*128+h];
  sl[h]=s[b*128+h];
  __syncthreads();
  for(int j=0;j<4;j++){
    int kh=h+j*128; int k=kh>>7;
    m2si[kh] = dots(mD_w + (size_t)kh*128, &ygl[k*128]) / asum[b*4+k] + mD_b[kh];
  }
  __syncthreads();
  float acc = B_b[h];
  { const float4* q=(const float4*)(B_w + (size_t)h*512);
#pragma unroll 8
    for(int i=0;i<128;i++){
      float4 p=q[i]; int base=i*4;
      acc=fmaf(p.x,m2si[base+0],acc); acc=fmaf(p.y,m2si[base+1],acc);
      acc=fmaf(p.z,m2si[base+2],acc); acc=fmaf(p.w,m2si[base+3],acc);
    }
  }
  float m2sv = ftanh(acc);
  m2sl[h]=m2sv;
  __syncthreads();
  float zacc = dots(gsA_w+(size_t)h*128, s2sl) + gsA_b[h];
  zacc      += dots(gsB_w+(size_t)h*128, m2sl) + gsB_b[h];
  float z = sigmoidf_(zacc);
  float hg = z*m2sl[h] + (1.f-z)*s2sl[h];
  hgl[h]=hg;
  __syncthreads();
  float gi[3], gh[3];
  for(int j=0;j<3;j++){
    gi[j]=dots(wih+(size_t)(h+j*128)*128, sl)+bih[h+j*128];
    gh[j]=dots(whh+(size_t)(h+j*128)*128, hgl)+bhh[h+j*128];
  }
  float r=sigmoidf_(gi[0]+gh[0]), z2=sigmoidf_(gi[1]+gh[1]);
  float nn=ftanh(gi[2]+r*gh[2]);
  out[(size_t)N_NODES*128 + b*128 + h] = (1.f-z2)*nn + z2*hg;
}

extern "C" void kernel_launch(void* const* d_in, const int* in_sizes, int n_in,
                              void* d_out, int out_size, void* d_ws, size_t ws_size,
                              hipStream_t stream){
  const float* v   = (const float*)d_in[0];
  const float* e   = (const float*)d_in[1];
  const float* s   = (const float*)d_in[2];
  const int* src  = (const int*)d_in[3];
  const int* dst  = (const int*)d_in[4];
  const int* graph_id = (const int*)d_in[5];
  const float* A_w=(const float*)d_in[6];  const float* A_b=(const float*)d_in[7];
  const float* B_w=(const float*)d_in[8];  const float* B_b=(const float*)d_in[9];
  const float* C_w=(const float*)d_in[10]; const float* C_b=(const float*)d_in[11];
  const float* E_w=(const float*)d_in[12]; const float* E_b=(const float*)d_in[13];
  const float* K_w=(const float*)d_in[14]; const float* K_b=(const float*)d_in[15];
  const float* mA_w=(const float*)d_in[16]; const float* mA_b=(const float*)d_in[17];
  const float* mB_w=(const float*)d_in[18]; const float* mB_b=(const float*)d_in[19];
  const float* mC_w=(const float*)d_in[20]; const float* mC_b=(const float*)d_in[21];
  const float* mD_w=(const float*)d_in[22]; const float* mD_b=(const float*)d_in[23];
  const float* gmA_w=(const float*)d_in[24]; const float* gmA_b=(const float*)d_in[25];
  const float* gmB_w=(const float*)d_in[26]; const float* gmB_b=(const float*)d_in[27];
  const float* gm_wih=(const float*)d_in[28]; const float* gm_bih=(const float*)d_in[29];
  const float* gm_whh=(const float*)d_in[30]; const float* gm_bhh=(const float*)d_in[31];
  const float* gsA_w=(const float*)d_in[32]; const float* gsA_b=(const float*)d_in[33];
  const float* gsB_w=(const float*)d_in[34]; const float* gsB_b=(const float*)d_in[35];
  const float* gs_wih=(const float*)d_in[36]; const float* gs_bih=(const float*)d_in[37];
  const float* gs_whh=(const float*)d_in[38]; const float* gs_bhh=(const float*)d_in[39];

  float* ws = (float*)d_ws;
  float* asum    = ws;                  // 256
  float* yg      = asum + 256;          // 32768
  float* s2s     = yg + 32768;          // 8192
  float* s2m_g   = s2s + 8192;          // 8192
  float* gmB_lin = s2m_g + 8192;        // 8192
  float* w2      = gmB_lin + 8192;      // 32768
  u16*   whi     = (u16*)(w2 + 32768);  // 212992 u16 (hi)
  u16*   wlo     = whi + 212992;        // 212992 u16 (lo)
  const size_t small_f = 256 + 32768 + 8192*3 + 32768 + 212992;   // 303360 floats

  size_t ws_f = ws_size / 4;

  hipMemsetAsync(asum, 0, (256 + 32768) * sizeof(float), stream);

  k_prep<<<832, 256, 0, stream>>>(E_w, gmA_w, gm_wih, gm_whh, mA_w, whi, wlo);
  k_sup <<<NB, 128, 0, stream>>>(s, A_w,A_b, C_w,C_b, mB_w,mB_b,mC_w, gmB_w,gmB_b,
                                 s2s, s2m_g, w2, gmB_lin);
  k_att <<<NB*CH64, 256, 0, stream>>>(v, w2, whi + 147456, wlo + 147456,
                                      mA_b, mC_b, asum, yg);
  k_sup2<<<NB, 128, 0, stream>>>(s, yg, asum, s2s, mD_w, mD_b, B_w,B_b,
                                 gsA_w,gsA_b, gsB_w,gsB_b,
                                 gs_wih,gs_bih, gs_whh,gs_bhh, (float*)d_out);

  // CSR-gather path: offs(100002) + cursor(100002) + slots(1M uint2) + full nbuf
  const size_t csr_off = small_f;                      // word offset, even
  const size_t csr_f   = 100002 + 100002 + 2000000;    // 2,200,004 words
  const size_t need_csr = csr_off + csr_f + (size_t)N_NODES*128;

  if(ws_f >= need_csr){
    u32*   offs   = (u32*)(ws + csr_off);
    u32*   cursor = offs + 100002;
    uint2* slots  = (uint2*)(cursor + 100002);
    float* nbuf   = (float*)(slots + 1000000);
    hipMemsetAsync(cursor, 0, (size_t)N_NODES*sizeof(u32), stream);
    k_hist<<<1024, 256, 0, stream>>>(dst, cursor);
    k_scan<<<1, 1024, 0, stream>>>(cursor, offs, cursor);
    k_fill<<<1024, 256, 0, stream>>>(src, dst, cursor, slots);
    k_gath<<<N_NODES, 128, 0, stream>>>(v, e, offs, slots, K_w, K_b, nbuf);
    k_node<<<(N_NODES+63)/64, 512, 0, stream>>>(v, graph_id, whi, wlo, E_b, gmA_b,
                                                gmB_lin, s2m_g, gm_bih, gm_bhh,
                                                nbuf, (float*)d_out, 0, N_NODES);
  } else {
    // fallback: chunked atomic scatter
    float* nbuf = (float*)(wlo + 212992);
    long avail = (ws_f > small_f) ? (long)(ws_f - small_f) : 0;
    long M = (avail / 128) & ~63L;
    if(M > N_NODES) M = N_NODES;
    if(M < 64) M = 64;
    for(long lo = 0; lo < N_NODES; lo += M){
      long cnt = N_NODES - lo; if(cnt > M) cnt = M;
      int ilo = (int)lo, icnt = (int)cnt;
      hipMemsetAsync(nbuf, 0, (size_t)icnt*128*sizeof(float), stream);
      k_edge<<<N_EDGES/16, 128, 0, stream>>>(v, e, src, dst, K_w, K_b, nbuf, ilo, ilo+icnt);
      k_node<<<(icnt+63)/64, 512, 0, stream>>>(v, graph_id, whi, wlo, E_b, gmA_b,
                                               gmB_lin, s2m_g, gm_bih, gm_bhh,
                                               nbuf, (float*)d_out, ilo, icnt);
    }
  }
}

// Round 7
// 922.634 us; speedup vs baseline: 2.2807x; 1.2665x over previous
//
#include <hip/hip_runtime.h>
#include <math.h>

typedef unsigned int u32;
typedef unsigned short u16;

#define N_NODES 100000
#define N_EDGES 1000000
#define NB      64
#define NODES_PER_G 1562   // N // B; graph 63 holds 1594
#define CH64 25            // ceil(1594/64)

typedef __attribute__((ext_vector_type(8))) short bf16x8;   // 8 bf16 = 4 VGPR
typedef __attribute__((ext_vector_type(4))) float f32x4;
#define MFMA16 __builtin_amdgcn_mfma_f32_16x16x32_bf16

__device__ __forceinline__ float sigmoidf_(float x){ return 1.f/(1.f+__expf(-x)); }
__device__ __forceinline__ float ftanh(float x){
  float e = __expf(-2.f*fabsf(x));
  float t = (1.f - e)/(1.f + e);
  return copysignf(t, x);
}
__device__ __forceinline__ float bfh(u16 h){ return __uint_as_float(((u32)h)<<16); }

__device__ __forceinline__ float dots(const float* w, const float* x){
  const float4* w4 = (const float4*)w;
  float a = 0.f;
#pragma unroll 8
  for(int i=0;i<32;i++){
    float4 t = w4[i];
    a = fmaf(t.x, x[4*i+0], a);
    a = fmaf(t.y, x[4*i+1], a);
    a = fmaf(t.z, x[4*i+2], a);
    a = fmaf(t.w, x[4*i+3], a);
  }
  return a;
}

// Dekker split: x = hi + lo, both bf16 (truncation); residual ~2^-16 relative
__device__ __forceinline__ void cvt2(float a, float b, u32 &hi, u32 &lo){
  u32 ab = __float_as_uint(a), bb = __float_as_uint(b);
  hi = (ab>>16) | (bb & 0xffff0000u);
  float ar = a - __uint_as_float(ab & 0xffff0000u);
  float br = b - __uint_as_float(bb & 0xffff0000u);
  lo = (__float_as_uint(ar)>>16) | (__float_as_uint(br) & 0xffff0000u);
}

// ------------- one-time weight split: fp32 -> bf16 hi/lo arrays in ws -------------
// flat u16 index:
// [0,32768)        E_w (128 x 256)
// [32768,49152)    gmA_w (128 x 128)
// [49152,147456)   GRU combined rows: row jr=j*128+h is 256 wide = [whh_jr | wih_jr]
// [147456,212992)  mA_w (512 x 128)
__global__ __launch_bounds__(256) void k_prep(const float* __restrict__ ew,
                    const float* __restrict__ ga,
                    const float* __restrict__ wih,
                    const float* __restrict__ whh,
                    const float* __restrict__ maw,
                    u16* __restrict__ hi, u16* __restrict__ lo){
  int i = blockIdx.x*256 + threadIdx.x;
  float x;
  if(i < 32768) x = ew[i];
  else if(i < 49152) x = ga[i-32768];
  else if(i < 147456){
    int rel = i - 49152;
    int jr = rel >> 8, c = rel & 255;
    x = (c < 128) ? whh[jr*128 + c] : wih[jr*128 + (c-128)];
  }
  else if(i < 212992) x = maw[i-147456];
  else return;
  u32 b = __float_as_uint(x);
  u16 h = (u16)(b>>16);
  float hf = __uint_as_float((u32)h<<16);
  float l = x - hf;
  hi[i] = h;
  lo[i] = (u16)(__float_as_uint(l)>>16);
}

// ---------------- per-graph precompute: s2s, s2m, w2(=dsup*mC), gmB_lin ----------
__global__ __launch_bounds__(128,4) void k_sup(const float* __restrict__ s,
                      const float* A_w, const float* A_b,
                      const float* C_w, const float* C_b,
                      const float* mB_w, const float* mB_b, const float* mC_w,
                      const float* gmB_w, const float* gmB_b,
                      float* s2s, float* s2m_g, float* w2, float* gmB_lin){
  int b = blockIdx.x, h = threadIdx.x;
  __shared__ float sb[128], s2ml[128];
  sb[h] = s[b*128+h];
  __syncthreads();
  s2s[b*128+h] = ftanh(dots(A_w + h*128, sb) + A_b[h]);
  float sm = ftanh(dots(C_w + h*128, sb) + C_b[h]);
  s2m_g[b*128+h] = sm; s2ml[h] = sm;
  for(int k=0;k<4;k++){
    float d = ftanh(dots(mB_w + (size_t)(k*128+h)*128, sb) + mB_b[k*128+h]);
    w2[b*512 + k*128 + h] = d * mC_w[k*128+h];
  }
  __syncthreads();
  gmB_lin[b*128+h] = dots(gmB_w + h*128, s2ml) + gmB_b[h];
}

// ------------- attention logits + weighted node-sum y, 64 nodes/block -------------
__global__ __launch_bounds__(256,3) void k_att(const float* __restrict__ v,
                      const float* __restrict__ w2,
                      const u16* __restrict__ mAhi, const u16* __restrict__ mAlo,
                      const float* __restrict__ mA_b, const float* __restrict__ mC_b,
                      float* __restrict__ asum, float* __restrict__ yg){
  int g = blockIdx.x / CH64, chunk = blockIdx.x % CH64;
  int start = g*NODES_PER_G, end = (g==NB-1)? N_NODES : start+NODES_PER_G;
  int node0 = start + chunk*64;
  int cnt = end - node0; if(cnt<=0) return; if(cnt>64) cnt=64;
  int t = threadIdx.x;
  int lane = t & 63, wv = t>>6;      // wv = head
  int lr = lane & 15, lg = lane >> 4;
  int koff = lg*8;

  __shared__ u16 XH[64][136], XL[64][136];
  __shared__ float ael[64][4];
  __shared__ float yq[4][4][128];
  __shared__ float wl2s[512], bAs[512];

  for(int i=t;i<64*32;i+=256){
    int n=i>>5, c=i&31;
    float4 val = (n<cnt) ? ((const float4*)(v + (size_t)(node0+n)*128))[c]
                         : make_float4(0.f,0.f,0.f,0.f);
    int cc = c<<2;
    u32 h01,l01,h23,l23;
    cvt2(val.x,val.y,h01,l01); cvt2(val.z,val.w,h23,l23);
    *(uint2*)&XH[n][cc] = make_uint2(h01,h23);
    *(uint2*)&XL[n][cc] = make_uint2(l01,l23);
  }
  for(int i=t;i<512;i+=256){ wl2s[i]=w2[g*512+i]; bAs[i]=mA_b[i]; }
  __syncthreads();

  float sr[4][4];
#pragma unroll
  for(int ng=0;ng<4;ng++){
#pragma unroll
    for(int r=0;r<4;r++) sr[ng][r]=0.f;
  }

  for(int tt=0; tt<8; tt++){
    int row = wv*128 + tt*16 + lr;
    const u16* bh  = mAhi + (size_t)row*128 + koff;
    const u16* bl_ = mAlo + (size_t)row*128 + koff;
    bf16x8 wh[4], wl[4];
#pragma unroll
    for(int ks=0;ks<4;ks++){
      wh[ks] = *(const bf16x8*)(bh  + ks*32);
      wl[ks] = *(const bf16x8*)(bl_ + ks*32);
    }
    float bb = bAs[row], ww = wl2s[row];
#pragma unroll
    for(int ng=0;ng<4;ng++){
      const u16* pah = &XH[ng*16+lr][koff];
      const u16* pal = &XL[ng*16+lr][koff];
      f32x4 acc = {0.f,0.f,0.f,0.f};
#pragma unroll
      for(int ks=0;ks<4;ks++){
        bf16x8 ah = *(const bf16x8*)(pah + ks*32);
        bf16x8 al = *(const bf16x8*)(pal + ks*32);
        acc = MFMA16(ah, wh[ks], acc, 0,0,0);
        acc = MFMA16(ah, wl[ks], acc, 0,0,0);
        acc = MFMA16(al, wh[ks], acc, 0,0,0);
      }
#pragma unroll
      for(int r=0;r<4;r++) sr[ng][r] += ftanh(acc[r]+bb)*ww;
    }
  }
#pragma unroll
  for(int ng=0;ng<4;ng++){
#pragma unroll
    for(int m=1;m<16;m<<=1){
      sr[ng][0] += __shfl_xor(sr[ng][0], m, 64);
      sr[ng][1] += __shfl_xor(sr[ng][1], m, 64);
      sr[ng][2] += __shfl_xor(sr[ng][2], m, 64);
      sr[ng][3] += __shfl_xor(sr[ng][3], m, 64);
    }
  }
  if(lr==0){
    float cb = mC_b[wv], la = 0.f;
#pragma unroll
    for(int ng=0;ng<4;ng++){
#pragma unroll
      for(int r=0;r<4;r++){
        int n = ng*16 + lg*4 + r;
        float ae = (n<cnt)? __expf(sr[ng][r]+cb) : 0.f;
        ael[n][wv] = ae; la += ae;
      }
    }
    atomicAdd(&asum[g*4+wv], la);
  }
  __syncthreads();

  {
    int q = t>>6, kk = (t>>4)&3, co = t&15;
    float a8[8];
#pragma unroll
    for(int j=0;j<8;j++) a8[j]=0.f;
    for(int n=q*16; n<q*16+16; n++){
      float w = ael[n][kk];
      bf16x8 hh = *(const bf16x8*)&XH[n][co*8];
      bf16x8 ll = *(const bf16x8*)&XL[n][co*8];
#pragma unroll
      for(int j=0;j<8;j++){
        float vv = bfh((u16)hh[j]) + bfh((u16)ll[j]);
        a8[j] = fmaf(w, vv, a8[j]);
      }
    }
#pragma unroll
    for(int j=0;j<8;j++) yq[q][kk][co*8+j] = a8[j];
  }
  __syncthreads();
  {
    int c = t&127, k0 = t>>7;
#pragma unroll
    for(int jj=0;jj<2;jj++){
      int k = k0 + jj*2;
      float y = yq[0][k][c]+yq[1][k][c]+yq[2][k][c]+yq[3][k][c];
      atomicAdd(&yg[(size_t)g*512 + k*128 + c], y);
    }
  }
}

// ---------------- CSR build: histogram, two-level scan, fill ----------------------
__global__ __launch_bounds__(256) void k_hist(const int* __restrict__ dst, u32* __restrict__ cnt){
  for(int i = blockIdx.x*256 + threadIdx.x; i < N_EDGES; i += 256*1024){
    int d = dst[i];
    if((u32)d < (u32)N_NODES) atomicAdd(&cnt[d], 1u);
  }
}

// local exclusive scan per 1024-chunk + chunk total
__global__ __launch_bounds__(1024) void k_scanA(const u32* __restrict__ cnt,
                        u32* __restrict__ offs, u32* __restrict__ tsum){
  __shared__ u32 wsum[16];
  int b = blockIdx.x, t = threadIdx.x, lane = t&63, w = t>>6;
  int i = b*1024 + t;
  u32 x = (i<N_NODES)? cnt[i] : 0u;
  u32 vsc = x;
#pragma unroll
  for(int o=1;o<64;o<<=1){ u32 y=__shfl_up(vsc,o,64); if(lane>=o) vsc+=y; }
  if(lane==63) wsum[w]=vsc;
  __syncthreads();
  if(w==0 && lane<16){
    u32 s = wsum[lane];
#pragma unroll
    for(int o=1;o<16;o<<=1){ u32 y=__shfl_up(s,o,64); if(lane>=o) s+=y; }
    wsum[lane]=s;
  }
  __syncthreads();
  u32 excl = (w>0 ? wsum[w-1] : 0u) + vsc - x;
  if(i<N_NODES) offs[i]=excl;
  if(t==1023) tsum[b] = wsum[15];
}

// add chunk base; write cursor copy; last block writes offs[N]
__global__ __launch_bounds__(1024) void k_scanB(const u32* __restrict__ tsum,
                        u32* __restrict__ offs, u32* __restrict__ cursor, int nb){
  __shared__ u32 base;
  int b = blockIdx.x, t = threadIdx.x;
  if(t==0){ u32 s=0; for(int j=0;j<b;j++) s+=tsum[j]; base=s; }
  __syncthreads();
  int i = b*1024 + t;
  if(i<N_NODES){ u32 o = offs[i]+base; offs[i]=o; cursor[i]=o; }
  if(b==nb-1 && t==0) offs[N_NODES] = base + tsum[b];
}

__global__ __launch_bounds__(256) void k_fill(const int* __restrict__ src, const int* __restrict__ dst,
                      u32* __restrict__ cursor, uint2* __restrict__ slots){
  for(int i = blockIdx.x*256 + threadIdx.x; i < N_EDGES; i += 256*1024){
    int d = dst[i];
    if((u32)d >= (u32)N_NODES) continue;
    int sj = src[i]; if((u32)sj >= (u32)N_NODES) sj = 0;
    u32 pos = atomicAdd(&cursor[d], 1u);
    slots[pos] = make_uint2((u32)sj, (u32)i);
  }
}

// ---------------- gather edge aggregation: one block per dst node ------------------
__global__ __launch_bounds__(128,8) void k_gath(const float* __restrict__ v,
                       const float* __restrict__ e,
                       const u32* __restrict__ offs, const uint2* __restrict__ slots,
                       const float* __restrict__ K_w, const float* __restrict__ K_b,
                       float* __restrict__ nbuf){
  int d = blockIdx.x;
  int h = threadIdx.x;
  u32 lo = offs[d], hi = offs[d+1];
  float4 kw0,kw1,kw2,kw3;
  { const float4* q=(const float4*)(K_w + h*16); kw0=q[0]; kw1=q[1]; kw2=q[2]; kw3=q[3]; }
  float kb = K_b[h];
  float acc = 0.f;
  __shared__ float el[16][16];
  __shared__ u32 ssrc[16];
  __shared__ u32 seid[16];
  for(u32 base=lo; base<hi; base+=16){
    int chunk = (int)(hi-base); if(chunk>16) chunk=16;
    if(h<chunk){ uint2 sd = slots[base+h]; ssrc[h]=sd.x; seid[h]=sd.y; }
    __syncthreads();
    for(int i=h; i<chunk*16; i+=128){ int j=i>>4, c=i&15; el[j][c] = e[(size_t)seid[j]*16 + c]; }
    __syncthreads();
    for(int j=0;j<chunk;j++){
      float kv = kb;
      kv=fmaf(kw0.x,el[j][0],kv);  kv=fmaf(kw0.y,el[j][1],kv);
      kv=fmaf(kw0.z,el[j][2],kv);  kv=fmaf(kw0.w,el[j][3],kv);
      kv=fmaf(kw1.x,el[j][4],kv);  kv=fmaf(kw1.y,el[j][5],kv);
      kv=fmaf(kw1.z,el[j][6],kv);  kv=fmaf(kw1.w,el[j][7],kv);
      kv=fmaf(kw2.x,el[j][8],kv);  kv=fmaf(kw2.y,el[j][9],kv);
      kv=fmaf(kw2.z,el[j][10],kv); kv=fmaf(kw2.w,el[j][11],kv);
      kv=fmaf(kw3.x,el[j][12],kv); kv=fmaf(kw3.y,el[j][13],kv);
      kv=fmaf(kw3.z,el[j][14],kv); kv=fmaf(kw3.w,el[j][15],kv);
      float vs = v[(size_t)ssrc[j]*128 + h];
      float val = kv*vs; val = (val>0.f)? val : 0.1f*val;
      acc += val;
    }
    __syncthreads();
  }
  nbuf[(size_t)d*128 + h] = acc;
}

// ---------------- fallback edge scatter (atomic), dst-range filtered ---------------
__global__ __launch_bounds__(128,4) void k_edge(const float* __restrict__ v, const float* __restrict__ e,
                       const int* __restrict__ src, const int* __restrict__ dst,
                       const float* K_w, const float* K_b,
                       float* __restrict__ nbuf, int lo, int hi){
  int h = threadIdx.x;
  int e0 = blockIdx.x * 16;
  __shared__ float el[16][16];
  __shared__ int sl[16], dl[16];
  for(int i=h;i<256;i+=128){ int ee=i>>4, c=i&15; el[ee][c]=e[(size_t)(e0+ee)*16+c]; }
  if(h<16){ sl[h]=src[e0+h]; dl[h]=dst[e0+h]; }
  float4 kw[4];
  { const float4* q=(const float4*)(K_w + h*16);
    kw[0]=q[0]; kw[1]=q[1]; kw[2]=q[2]; kw[3]=q[3]; }
  float kb = K_b[h];
  __syncthreads();
  for(int j=0;j<16;j++){
    int dj = dl[j];
    if(dj < lo || dj >= hi) continue;
    int sj = sl[j]; if((u32)sj >= (u32)N_NODES) sj = 0;
    float kv=kb;
#pragma unroll
    for(int i=0;i<4;i++){
      float4 t = kw[i];
      kv = fmaf(t.x, el[j][4*i+0], kv);
      kv = fmaf(t.y, el[j][4*i+1], kv);
      kv = fmaf(t.z, el[j][4*i+2], kv);
      kv = fmaf(t.w, el[j][4*i+3], kv);
    }
    float vs = v[(size_t)sj*128+h];
    float val = kv*vs; val = (val>0.f)? val : 0.1f*val;
    atomicAdd(&nbuf[(size_t)(dj-lo)*128+h], val);
  }
}

// ---------------- fused node pipeline, 64 nodes/block, register-diet GRU ----------
// 512 thr / 8 waves; wave wv owns h-tile wv for all phases, ng=0..3 node groups.
// GRU r,z gates fused via K=256 combined weights [whh|wih] @ [hgate|v] (one acc set);
// n gate split (needs gi,gh separately). hgate reconstructed from LDS hi+lo at the end.
__global__ __launch_bounds__(512,4) void k_node(
    const float* __restrict__ v, const int* __restrict__ graph_id,
    const u16* __restrict__ whi, const u16* __restrict__ wlo,
    const float* __restrict__ E_b, const float* __restrict__ gmA_b,
    const float* __restrict__ gmB_lin, const float* __restrict__ s2m_g,
    const float* __restrict__ bih, const float* __restrict__ bhh,
    const float* __restrict__ nbuf, float* __restrict__ out, int lo_, int lim){
  int t = threadIdx.x;
  int nl0 = blockIdx.x*64;
  int node0 = lo_ + nl0;
  int cnt = lim - nl0; if(cnt > 64) cnt = 64;
  int lane = t & 63, wv = t>>6;
  int lr = lane & 15, lg = lane >> 4;
  int koff = lg*8;
  int hh = wv*16 + lr;

  __shared__ u16 XH[64][264];   // cols 0..127: sve -> m2m -> hgate ; 128..255: v
  __shared__ u16 XL[64][264];
  __shared__ int gid[64];

  for(int i=t; i<64*64; i+=512){
    int n = i>>6, c4 = i&63;
    float4 val;
    if(n < cnt){
      val = (c4<32) ? ((const float4*)(nbuf + (size_t)(nl0+n)*128))[c4]
                    : ((const float4*)(v + (size_t)(node0+n)*128))[c4-32];
    } else val = make_float4(0.f,0.f,0.f,0.f);
    int c = c4<<2;
    u32 h01,l01,h23,l23;
    cvt2(val.x, val.y, h01, l01);
    cvt2(val.z, val.w, h23, l23);
    *(uint2*)&XH[n][c] = make_uint2(h01, h23);
    *(uint2*)&XL[n][c] = make_uint2(l01, l23);
  }
  if(t<64) gid[t] = (t<cnt) ? (graph_id[node0+t] & 63) : 0;
  __syncthreads();

  // ---- phase 1: m2m = leaky(E_w @ [sve; v] + E_b), K=256
  f32x4 m2m[4];
  {
    f32x4 acc[4];
#pragma unroll
    for(int ng=0;ng<4;ng++){ f32x4 z={0.f,0.f,0.f,0.f}; acc[ng]=z; }
    const u16* bh = whi + (size_t)hh*256 + koff;
    const u16* bl = wlo + (size_t)hh*256 + koff;
#pragma unroll
    for(int ks=0; ks<8; ks++){
      bf16x8 wh_ = *(const bf16x8*)(bh + ks*32);
      bf16x8 wl_ = *(const bf16x8*)(bl + ks*32);
#pragma unroll
      for(int ng=0;ng<4;ng++){
        bf16x8 ah = *(const bf16x8*)&XH[ng*16+lr][koff + ks*32];
        bf16x8 al = *(const bf16x8*)&XL[ng*16+lr][koff + ks*32];
        acc[ng] = MFMA16(ah, wh_, acc[ng], 0,0,0);
        acc[ng] = MFMA16(ah, wl_, acc[ng], 0,0,0);
        acc[ng] = MFMA16(al, wh_, acc[ng], 0,0,0);
      }
    }
    __syncthreads();
    float eb = E_b[hh];
#pragma unroll
    for(int ng=0;ng<4;ng++){
#pragma unroll
      for(int r=0;r<4;r++){
        float m = acc[ng][r] + eb;
        m = (m>0.f)? m : 0.1f*m;
        m2m[ng][r] = m;
        int n = ng*16 + lg*4 + r;
        u32 mb = __float_as_uint(m);
        u16 mh = (u16)(mb>>16);
        XH[n][hh] = mh;
        float mlr = m - __uint_as_float((u32)mh<<16);
        XL[n][hh] = (u16)(__float_as_uint(mlr)>>16);
      }
    }
    __syncthreads();
  }

  // ---- phase 2: z = sigmoid(gmA@m2m + gmA_b + gmB_lin); hgate = z*s2m + (1-z)*m2m
  {
    f32x4 acc[4];
#pragma unroll
    for(int ng=0;ng<4;ng++){ f32x4 z={0.f,0.f,0.f,0.f}; acc[ng]=z; }
    const u16* bh = whi + 32768 + (size_t)hh*128 + koff;
    const u16* bl = wlo + 32768 + (size_t)hh*128 + koff;
#pragma unroll
    for(int ks=0; ks<4; ks++){
      bf16x8 wh_ = *(const bf16x8*)(bh + ks*32);
      bf16x8 wl_ = *(const bf16x8*)(bl + ks*32);
#pragma unroll
      for(int ng=0;ng<4;ng++){
        bf16x8 ah = *(const bf16x8*)&XH[ng*16+lr][koff + ks*32];
        bf16x8 al = *(const bf16x8*)&XL[ng*16+lr][koff + ks*32];
        acc[ng] = MFMA16(ah, wh_, acc[ng], 0,0,0);
        acc[ng] = MFMA16(ah, wl_, acc[ng], 0,0,0);
        acc[ng] = MFMA16(al, wh_, acc[ng], 0,0,0);
      }
    }
    __syncthreads();
    float ab = gmA_b[hh];
#pragma unroll
    for(int ng=0;ng<4;ng++){
#pragma unroll
      for(int r=0;r<4;r++){
        int n = ng*16 + lg*4 + r;
        int g = gid[n];
        float z = sigmoidf_(acc[ng][r] + ab + gmB_lin[g*128+hh]);
        float hg = z*s2m_g[g*128+hh] + (1.f-z)*m2m[ng][r];
        u32 mb = __float_as_uint(hg);
        u16 mh = (u16)(mb>>16);
        XH[n][hh] = mh;
        float mlr = hg - __uint_as_float((u32)mh<<16);
        XL[n][hh] = (u16)(__float_as_uint(mlr)>>16);
      }
    }
    __syncthreads();
  }

  // ---- phase 3: GRU. combined rows [whh|wih] @ X=[hgate|v]; gates r, n, z --------
  {
    const u16* wGh = whi + 49152;
    const u16* wGl = wlo + 49152;
    f32x4 rr[4], nn[4];

    // gate r (j=0): fused K=256
    {
      f32x4 acc[4];
#pragma unroll
      for(int ng=0;ng<4;ng++){ f32x4 z={0.f,0.f,0.f,0.f}; acc[ng]=z; }
      const u16* ph = wGh + (size_t)hh*256 + koff;
      const u16* pl = wGl + (size_t)hh*256 + koff;
#pragma unroll
      for(int ks=0; ks<8; ks++){
        bf16x8 wh_ = *(const bf16x8*)(ph + ks*32);
        bf16x8 wl_ = *(const bf16x8*)(pl + ks*32);
#pragma unroll
        for(int ng=0;ng<4;ng++){
          bf16x8 ah = *(const bf16x8*)&XH[ng*16+lr][koff + ks*32];
          bf16x8 al = *(const bf16x8*)&XL[ng*16+lr][koff + ks*32];
          acc[ng] = MFMA16(ah, wh_, acc[ng], 0,0,0);
          acc[ng] = MFMA16(ah, wl_, acc[ng], 0,0,0);
          acc[ng] = MFMA16(al, wh_, acc[ng], 0,0,0);
        }
      }
      float bsum = bih[hh] + bhh[hh];
#pragma unroll
      for(int ng=0;ng<4;ng++)
#pragma unroll
        for(int r=0;r<4;r++) rr[ng][r] = sigmoidf_(acc[ng][r] + bsum);
    }

    // gate n (j=2): split halves (gh from hgate/whh, gi from v/wih)
    {
      f32x4 aH[4], aI[4];
#pragma unroll
      for(int ng=0;ng<4;ng++){ f32x4 z={0.f,0.f,0.f,0.f}; aH[ng]=z; aI[ng]=z; }
      const u16* ph = wGh + (size_t)(256+hh)*256 + koff;
      const u16* pl = wGl + (size_t)(256+hh)*256 + koff;
#pragma unroll
      for(int ks=0; ks<4; ks++){
        bf16x8 wh_ = *(const bf16x8*)(ph + ks*32);
        bf16x8 wl_ = *(const bf16x8*)(pl + ks*32);
#pragma unroll
        for(int ng=0;ng<4;ng++){
          bf16x8 ah = *(const bf16x8*)&XH[ng*16+lr][koff + ks*32];
          bf16x8 al = *(const bf16x8*)&XL[ng*16+lr][koff + ks*32];
          aH[ng] = MFMA16(ah, wh_, aH[ng], 0,0,0);
          aH[ng] = MFMA16(ah, wl_, aH[ng], 0,0,0);
          aH[ng] = MFMA16(al, wh_, aH[ng], 0,0,0);
        }
      }
#pragma unroll
      for(int ks=4; ks<8; ks++){
        bf16x8 wh_ = *(const bf16x8*)(ph + ks*32);
        bf16x8 wl_ = *(const bf16x8*)(pl + ks*32);
#pragma unroll
        for(int ng=0;ng<4;ng++){
          bf16x8 ah = *(const bf16x8*)&XH[ng*16+lr][koff + ks*32];
          bf16x8 al = *(const bf16x8*)&XL[ng*16+lr][koff + ks*32];
          aI[ng] = MFMA16(ah, wh_, aI[ng], 0,0,0);
          aI[ng] = MFMA16(ah, wl_, aI[ng], 0,0,0);
          aI[ng] = MFMA16(al, wh_, aI[ng], 0,0,0);
        }
      }
      float bI = bih[256+hh], bH = bhh[256+hh];
#pragma unroll
      for(int ng=0;ng<4;ng++)
#pragma unroll
        for(int r=0;r<4;r++)
          nn[ng][r] = ftanh((aI[ng][r]+bI) + rr[ng][r]*(aH[ng][r]+bH));
    }

    // gate z (j=1): fused K=256, then combine and write
    {
      f32x4 acc[4];
#pragma unroll
      for(int ng=0;ng<4;ng++){ f32x4 z={0.f,0.f,0.f,0.f}; acc[ng]=z; }
      const u16* ph = wGh + (size_t)(128+hh)*256 + koff;
      const u16* pl = wGl + (size_t)(128+hh)*256 + koff;
#pragma unroll
      for(int ks=0; ks<8; ks++){
        bf16x8 wh_ = *(const bf16x8*)(ph + ks*32);
        bf16x8 wl_ = *(const bf16x8*)(pl + ks*32);
#pragma unroll
        for(int ng=0;ng<4;ng++){
          bf16x8 ah = *(const bf16x8*)&XH[ng*16+lr][koff + ks*32];
          bf16x8 al = *(const bf16x8*)&XL[ng*16+lr][koff + ks*32];
          acc[ng] = MFMA16(ah, wh_, acc[ng], 0,0,0);
          acc[ng] = MFMA16(ah, wl_, acc[ng], 0,0,0);
          acc[ng] = MFMA16(al, wh_, acc[ng], 0,0,0);
        }
      }
      float bsum = bih[128+hh] + bhh[128+hh];
#pragma unroll
      for(int ng=0;ng<4;ng++){
#pragma unroll
        for(int r=0;r<4;r++){
          float zz = sigmoidf_(acc[ng][r] + bsum);
          int n = ng*16 + lg*4 + r;
          float hgv = bfh(XH[n][hh]) + bfh(XL[n][hh]);   // exact hi+lo reconstruct
          if(n < cnt)
            out[(size_t)(node0+n)*128 + hh] = (1.f-zz)*nn[ng][r] + zz*hgv;
        }
      }
    }
  }
}

// ---------------- supernode finish: m2s (incl. hoisted mD), gate, GRU -------------
__global__ __launch_bounds__(128,4) void k_sup2(const float* __restrict__ s,
                       const float* __restrict__ yg, const float* __restrict__ asum,
                       const float* __restrict__ s2s,
                       const float* mD_w, const float* mD_b,
                       const float* B_w, const float* B_b,
                       const float* gsA_w, const float* gsA_b,
                       const float* gsB_w, const float* gsB_b,
                       const float* wih, const float* bih, const float* whh, const float* bhh,
                       float* __restrict__ out){
  int b=blockIdx.x, h=threadIdx.x;
  __shared__ float ygl[512], m2si[512], m2sl[128], s2sl[128], sl[128], hgl[128];
  for(int j=0;j<4;j++){ int kh=h+j*128; ygl[kh]=yg[b*512+kh]; }
  s2sl[h]=s2s[b*128+h];
  sl[h]=s[b*128+h];
  __syncthreads();
  for(int j=0;j<4;j++){
    int kh=h+j*128; int k=kh>>7;
    m2si[kh] = dots(mD_w + (size_t)kh*128, &ygl[k*128]) / asum[b*4+k] + mD_b[kh];
  }
  __syncthreads();
  float acc = B_b[h];
  { const float4* q=(const float4*)(B_w + (size_t)h*512);
#pragma unroll 8
    for(int i=0;i<128;i++){
      float4 p=q[i]; int base=i*4;
      acc=fmaf(p.x,m2si[base+0],acc); acc=fmaf(p.y,m2si[base+1],acc);
      acc=fmaf(p.z,m2si[base+2],acc); acc=fmaf(p.w,m2si[base+3],acc);
    }
  }
  float m2sv = ftanh(acc);
  m2sl[h]=m2sv;
  __syncthreads();
  float zacc = dots(gsA_w+(size_t)h*128, s2sl) + gsA_b[h];
  zacc      += dots(gsB_w+(size_t)h*128, m2sl) + gsB_b[h];
  float z = sigmoidf_(zacc);
  float hg = z*m2sl[h] + (1.f-z)*s2sl[h];
  hgl[h]=hg;
  __syncthreads();
  float gi[3], gh[3];
  for(int j=0;j<3;j++){
    gi[j]=dots(wih+(size_t)(h+j*128)*128, sl)+bih[h+j*128];
    gh[j]=dots(whh+(size_t)(h+j*128)*128, hgl)+bhh[h+j*128];
  }
  float r=sigmoidf_(gi[0]+gh[0]), z2=sigmoidf_(gi[1]+gh[1]);
  float nn=ftanh(gi[2]+r*gh[2]);
  out[(size_t)N_NODES*128 + b*128 + h] = (1.f-z2)*nn + z2*hg;
}

extern "C" void kernel_launch(void* const* d_in, const int* in_sizes, int n_in,
                              void* d_out, int out_size, void* d_ws, size_t ws_size,
                              hipStream_t stream){
  const float* v   = (const float*)d_in[0];
  const float* e   = (const float*)d_in[1];
  const float* s   = (const float*)d_in[2];
  const int* src  = (const int*)d_in[3];
  const int* dst  = (const int*)d_in[4];
  const int* graph_id = (const int*)d_in[5];
  const float* A_w=(const float*)d_in[6];  const float* A_b=(const float*)d_in[7];
  const float* B_w=(const float*)d_in[8];  const float* B_b=(const float*)d_in[9];
  const float* C_w=(const float*)d_in[10]; const float* C_b=(const float*)d_in[11];
  const float* E_w=(const float*)d_in[12]; const float* E_b=(const float*)d_in[13];
  const float* K_w=(const float*)d_in[14]; const float* K_b=(const float*)d_in[15];
  const float* mA_w=(const float*)d_in[16]; const float* mA_b=(const float*)d_in[17];
  const float* mB_w=(const float*)d_in[18]; const float* mB_b=(const float*)d_in[19];
  const float* mC_w=(const float*)d_in[20]; const float* mC_b=(const float*)d_in[21];
  const float* mD_w=(const float*)d_in[22]; const float* mD_b=(const float*)d_in[23];
  const float* gmA_w=(const float*)d_in[24]; const float* gmA_b=(const float*)d_in[25];
  const float* gmB_w=(const float*)d_in[26]; const float* gmB_b=(const float*)d_in[27];
  const float* gm_wih=(const float*)d_in[28]; const float* gm_bih=(const float*)d_in[29];
  const float* gm_whh=(const float*)d_in[30]; const float* gm_bhh=(const float*)d_in[31];
  const float* gsA_w=(const float*)d_in[32]; const float* gsA_b=(const float*)d_in[33];
  const float* gsB_w=(const float*)d_in[34]; const float* gsB_b=(const float*)d_in[35];
  const float* gs_wih=(const float*)d_in[36]; const float* gs_bih=(const float*)d_in[37];
  const float* gs_whh=(const float*)d_in[38]; const float* gs_bhh=(const float*)d_in[39];

  float* ws = (float*)d_ws;
  float* asum    = ws;                  // 256
  float* yg      = asum + 256;          // 32768
  float* s2s     = yg + 32768;          // 8192
  float* s2m_g   = s2s + 8192;          // 8192
  float* gmB_lin = s2m_g + 8192;        // 8192
  float* w2      = gmB_lin + 8192;      // 32768
  u16*   whi     = (u16*)(w2 + 32768);  // 212992 u16 (hi)
  u16*   wlo     = whi + 212992;        // 212992 u16 (lo)
  const size_t small_f = 256 + 32768 + 8192*3 + 32768 + 212992;   // 303360 floats

  size_t ws_f = ws_size / 4;

  hipMemsetAsync(asum, 0, (256 + 32768) * sizeof(float), stream);

  k_prep<<<832, 256, 0, stream>>>(E_w, gmA_w, gm_wih, gm_whh, mA_w, whi, wlo);
  k_sup <<<NB, 128, 0, stream>>>(s, A_w,A_b, C_w,C_b, mB_w,mB_b,mC_w, gmB_w,gmB_b,
                                 s2s, s2m_g, w2, gmB_lin);
  k_att <<<NB*CH64, 256, 0, stream>>>(v, w2, whi + 147456, wlo + 147456,
                                      mA_b, mC_b, asum, yg);
  k_sup2<<<NB, 128, 0, stream>>>(s, yg, asum, s2s, mD_w, mD_b, B_w,B_b,
                                 gsA_w,gsA_b, gsB_w,gsB_b,
                                 gs_wih,gs_bih, gs_whh,gs_bhh, (float*)d_out);

  // CSR-gather path: offs(100002) + cursor(100002) + tsum(128) + slots(1M uint2) + nbuf
  const int SCAN_NB = (N_NODES + 1023) / 1024;         // 98
  const size_t csr_off = small_f;
  const size_t csr_f   = 100002 + 100002 + 128 + 2000000;
  const size_t need_csr = csr_off + csr_f + (size_t)N_NODES*128;

  if(ws_f >= need_csr){
    u32*   offs   = (u32*)(ws + csr_off);
    u32*   cursor = offs + 100002;
    u32*   tsum   = cursor + 100002;
    uint2* slots  = (uint2*)(tsum + 128);
    float* nbuf   = (float*)(slots + 1000000);
    hipMemsetAsync(cursor, 0, (size_t)N_NODES*sizeof(u32), stream);
    k_hist<<<1024, 256, 0, stream>>>(dst, cursor);
    k_scanA<<<SCAN_NB, 1024, 0, stream>>>(cursor, offs, tsum);
    k_scanB<<<SCAN_NB, 1024, 0, stream>>>(tsum, offs, cursor, SCAN_NB);
    k_fill<<<1024, 256, 0, stream>>>(src, dst, cursor, slots);
    k_gath<<<N_NODES, 128, 0, stream>>>(v, e, offs, slots, K_w, K_b, nbuf);
    k_node<<<(N_NODES+63)/64, 512, 0, stream>>>(v, graph_id, whi, wlo, E_b, gmA_b,
                                                gmB_lin, s2m_g, gm_bih, gm_bhh,
                                                nbuf, (float*)d_out, 0, N_NODES);
  } else {
    // fallback: chunked atomic scatter
    float* nbuf = (float*)(wlo + 212992);
    long avail = (ws_f > small_f) ? (long)(ws_f - small_f) : 0;
    long M = (avail / 128) & ~63L;
    if(M > N_NODES) M = N_NODES;
    if(M < 64) M = 64;
    for(long lo = 0; lo < N_NODES; lo += M){
      long cnt = N_NODES - lo; if(cnt > M) cnt = M;
      int ilo = (int)lo, icnt = (int)cnt;
      hipMemsetAsync(nbuf, 0, (size_t)icnt*128*sizeof(float), stream);
      k_edge<<<N_EDGES/16, 128, 0, stream>>>(v, e, src, dst, K_w, K_b, nbuf, ilo, ilo+icnt);
      k_node<<<(icnt+63)/64, 512, 0, stream>>>(v, graph_id, whi, wlo, E_b, gmA_b,
                                               gmB_lin, s2m_g, gm_bih, gm_bhh,
                                               nbuf, (float*)d_out, ilo, icnt);
    }
  }
}